// Round 2
// baseline (1074.636 us; speedup 1.0000x reference)
//
#include <hip/hip_runtime.h>
#include <math.h>

#define ROWS 65536        // 4*128*128
#define HDIM 512          // 8*64
#define KDD 192

// ---------------- LayerNorm over last dim (128) ----------------
__global__ __launch_bounds__(128) void k_ln(const float* __restrict__ x,
                                            const float* __restrict__ g,
                                            const float* __restrict__ bb,
                                            float* __restrict__ y) {
  int row = blockIdx.x;
  int t = threadIdx.x;
  float v = x[(size_t)row * 128 + t];
  float s = v, s2 = v * v;
  for (int off = 32; off > 0; off >>= 1) {
    s += __shfl_down(s, off, 64);
    s2 += __shfl_down(s2, off, 64);
  }
  __shared__ float ps[2], ps2[2];
  int wid = t >> 6, lane = t & 63;
  if (lane == 0) { ps[wid] = s; ps2[wid] = s2; }
  __syncthreads();
  float S = ps[0] + ps[1], S2 = ps2[0] + ps2[1];
  float mean = S * (1.f / 128.f);
  float var = S2 * (1.f / 128.f) - mean * mean;
  float r = rsqrtf(var + 1e-5f);
  y[(size_t)row * 128 + t] = (v - mean) * r * g[t] + bb[t];
}

// ---------------- Generic fp32 GEMM: C[M,N] = A[M,K] @ B[K,N] ----------------
// tile 64x64, K-step 16, 256 threads, 4x4 per thread.
// EPI==1: instance-norm + exact gelu epilogue: gelu((acc - m[i]*s[n]) * r[i]), i=row>>7
template <int EPI>
__global__ __launch_bounds__(256) void k_gemm(const float* __restrict__ A,
                                              const float* __restrict__ Bm,
                                              float* __restrict__ C,
                                              int M, int N, int K,
                                              int lda, int ldb, int ldc,
                                              const float* __restrict__ rr,
                                              const float* __restrict__ mm,
                                              const float* __restrict__ ss) {
  __shared__ float As[16][64];
  __shared__ float Bs[16][64];
  int tid = threadIdx.x;
  int n0 = blockIdx.x * 64, m0 = blockIdx.y * 64;
  int tx = tid & 15, ty = tid >> 4;
  float acc[4][4] = {};
  int la_m = tid >> 2;
  int la_k = (tid & 3) * 4;
  int lb_k = tid >> 4;
  int lb_n = (tid & 15) * 4;
  for (int k0 = 0; k0 < K; k0 += 16) {
    float4 a4 = *(const float4*)(A + (size_t)(m0 + la_m) * lda + k0 + la_k);
    As[la_k + 0][la_m] = a4.x;
    As[la_k + 1][la_m] = a4.y;
    As[la_k + 2][la_m] = a4.z;
    As[la_k + 3][la_m] = a4.w;
    float4 b4 = *(const float4*)(Bm + (size_t)(k0 + lb_k) * ldb + n0 + lb_n);
    *(float4*)&Bs[lb_k][lb_n] = b4;
    __syncthreads();
#pragma unroll
    for (int kk = 0; kk < 16; kk++) {
      float4 av = *(const float4*)&As[kk][ty * 4];
      float4 bv = *(const float4*)&Bs[kk][tx * 4];
      float a[4] = {av.x, av.y, av.z, av.w};
      float b[4] = {bv.x, bv.y, bv.z, bv.w};
#pragma unroll
      for (int i = 0; i < 4; i++)
#pragma unroll
        for (int j = 0; j < 4; j++) acc[i][j] += a[i] * b[j];
    }
    __syncthreads();
  }
#pragma unroll
  for (int i = 0; i < 4; i++) {
    int m = m0 + ty * 4 + i;
    float vv[4];
#pragma unroll
    for (int j = 0; j < 4; j++) {
      float vacc = acc[i][j];
      if (EPI == 1) {
        int bi = m >> 7;
        int n = n0 + tx * 4 + j;
        float val = (vacc - mm[bi] * ss[n]) * rr[bi];
        vacc = val * 0.5f * (1.f + erff(val * 0.70710678f));
      }
      vv[j] = vacc;
    }
    float4 o;
    o.x = vv[0]; o.y = vv[1]; o.z = vv[2]; o.w = vv[3];
    *(float4*)(C + (size_t)m * ldc + n0 + tx * 4) = o;
  }
}

// ---------------- means of un over ny / nx ----------------
__global__ __launch_bounds__(128) void k_meanx(const float* __restrict__ un, float* __restrict__ mx) {
  int bi = blockIdx.x;  // b*128 + i
  int c = threadIdx.x;
  const float* p = un + (size_t)bi * 128 * 128 + c;
  float s = 0;
  for (int j = 0; j < 128; j++) s += p[(size_t)j * 128];
  mx[(size_t)bi * 128 + c] = s * (1.f / 128.f);
}
__global__ __launch_bounds__(128) void k_meany(const float* __restrict__ un, float* __restrict__ my) {
  int bj = blockIdx.x;  // b*128 + j
  int b = bj >> 7, j = bj & 127;
  const float* p = un + (size_t)b * 2097152 + (size_t)j * 128 + threadIdx.x;
  float s = 0;
  for (int i = 0; i < 128; i++) s += p[(size_t)i * 16384];
  my[(size_t)bj * 128 + threadIdx.x] = s * (1.f / 128.f);
}

// ---------------- pooling MLP: one row per block (W = Win@px_Win combined) ----------------
__global__ __launch_bounds__(128) void k_pool(const float* __restrict__ in,   // [R,128]
                                              const float* __restrict__ Wc,   // [128,128]
                                              const float* __restrict__ g,
                                              const float* __restrict__ bb,
                                              const float* __restrict__ W1,   // [128,256]
                                              const float* __restrict__ b1,
                                              const float* __restrict__ W2,   // [128,64]
                                              const float* __restrict__ b2,
                                              float* __restrict__ out) {      // [R,64]
  int row = blockIdx.x;
  int t = threadIdx.x;
  __shared__ float xin[128], h1[128], h3[128];
  __shared__ float ps[2], ps2[2];
  xin[t] = in[(size_t)row * 128 + t];
  __syncthreads();
  float a = 0;
  for (int k = 0; k < 128; k++) a += xin[k] * Wc[k * 128 + t];
  float s = a, s2 = a * a;
  for (int off = 32; off > 0; off >>= 1) {
    s += __shfl_down(s, off, 64);
    s2 += __shfl_down(s2, off, 64);
  }
  if ((t & 63) == 0) { ps[t >> 6] = s; ps2[t >> 6] = s2; }
  __syncthreads();
  float S = ps[0] + ps[1], S2 = ps2[0] + ps2[1];
  float mean = S * (1.f / 128.f);
  float var = S2 * (1.f / 128.f) - mean * mean;
  float r = rsqrtf(var + 1e-5f);
  h1[t] = (a - mean) * r * g[t] + bb[t];
  __syncthreads();
  float u1 = b1[t], u2 = b1[t + 128];
  for (int k = 0; k < 128; k++) {
    float hv = h1[k];
    u1 += hv * W1[k * 256 + t];
    u2 += hv * W1[k * 256 + t + 128];
  }
  float ge = u1 * 0.5f * (1.f + erff(u1 * 0.70710678f));
  h3[t] = ge * u2;
  __syncthreads();
  if (t < 64) {
    float o = b2[t];
    for (int k = 0; k < 128; k++) o += h3[k] * W2[k * 64 + t];
    out[(size_t)row * 64 + t] = o;
  }
}

// ---------------- rotary: qk [b,n,3072] -> qr,kr [b,h,n,192] ----------------
__global__ __launch_bounds__(192) void k_rotary(const float* __restrict__ qk,
                                                const float* __restrict__ pos,
                                                float* __restrict__ qr,
                                                float* __restrict__ kr) {
  int bn = blockIdx.x;  // b*128 + n
  int b = bn >> 7, n = bn & 127;
  int d = threadIdx.x;  // 0..191
  int fi = d % 96;
  float inv = expf(-logf(10000.f) * ((float)fi / 96.f));
  float f = pos[n] * 64.f * inv;
  float cs = cosf(f), sn = sinf(f);
  int partner = d < 96 ? d + 96 : d - 96;
  float sgn = d < 96 ? -1.f : 1.f;
  for (int h = 0; h < 8; h++) {
    float q = qk[(size_t)bn * 3072 + h * 192 + d];
    float qp = qk[(size_t)bn * 3072 + h * 192 + partner];
    float kx = qk[(size_t)bn * 3072 + 1536 + h * 192 + d];
    float kp = qk[(size_t)bn * 3072 + 1536 + h * 192 + partner];
    size_t o = ((size_t)(b * 8 + h) * 128 + n) * 192 + d;
    qr[o] = q * cs + sgn * qp * sn;
    kr[o] = kx * cs + sgn * kp * sn;
  }
}

// ---------------- batched Q@K^T per (b,h): [128,192]x[128,192]^T -> [128,128] ----------------
__global__ __launch_bounds__(256) void k_qkt(const float* __restrict__ Q,
                                             const float* __restrict__ Kt,
                                             float* __restrict__ C) {
  int bh = blockIdx.z;
  const float* Qb = Q + (size_t)bh * 128 * KDD;
  const float* Kb = Kt + (size_t)bh * 128 * KDD;
  float* Cb = C + (size_t)bh * 128 * 128;
  __shared__ float As[16][64];
  __shared__ float Bs[16][64];
  int tid = threadIdx.x;
  int i0 = blockIdx.y * 64, j0 = blockIdx.x * 64;
  int tx = tid & 15, ty = tid >> 4;
  float acc[4][4] = {};
  int l_m = tid >> 2, l_k = (tid & 3) * 4;
  for (int k0 = 0; k0 < KDD; k0 += 16) {
    float4 a4 = *(const float4*)(Qb + (size_t)(i0 + l_m) * KDD + k0 + l_k);
    As[l_k + 0][l_m] = a4.x; As[l_k + 1][l_m] = a4.y;
    As[l_k + 2][l_m] = a4.z; As[l_k + 3][l_m] = a4.w;
    float4 b4 = *(const float4*)(Kb + (size_t)(j0 + l_m) * KDD + k0 + l_k);
    Bs[l_k + 0][l_m] = b4.x; Bs[l_k + 1][l_m] = b4.y;
    Bs[l_k + 2][l_m] = b4.z; Bs[l_k + 3][l_m] = b4.w;
    __syncthreads();
#pragma unroll
    for (int kk = 0; kk < 16; kk++) {
      float4 av = *(const float4*)&As[kk][ty * 4];
      float4 bv = *(const float4*)&Bs[kk][tx * 4];
      float a[4] = {av.x, av.y, av.z, av.w};
      float b[4] = {bv.x, bv.y, bv.z, bv.w};
#pragma unroll
      for (int i = 0; i < 4; i++)
#pragma unroll
        for (int j = 0; j < 4; j++) acc[i][j] += a[i] * b[j];
    }
    __syncthreads();
  }
#pragma unroll
  for (int i = 0; i < 4; i++) {
    float4 o;
    o.x = acc[i][0]; o.y = acc[i][1]; o.z = acc[i][2]; o.w = acc[i][3];
    *(float4*)(Cb + (size_t)(i0 + ty * 4 + i) * 128 + j0 + tx * 4) = o;
  }
}

// ---------------- t1[h,i,m,c] = sum_j kx[h,i,j] * v_b[(j,m), h*64+c]  (single batch) ----------------
__global__ __launch_bounds__(256) void k_t1(const float* __restrict__ KX,   // [8,128,128] this batch
                                            const float* __restrict__ V,    // [16384, 512] this batch
                                            float* __restrict__ T1) {       // [8,128,128,64]
  int h = blockIdx.z;
  int m = blockIdx.x;
  int i0 = blockIdx.y * 64;
  const float* A = KX + (size_t)h * 16384;
  const float* Bp = V + (size_t)m * 512 + h * 64;
  float* Cp = T1 + (size_t)h * 1048576 + (size_t)m * 64;
  __shared__ float As[16][64];
  __shared__ float Bs[16][64];
  int tid = threadIdx.x, tx = tid & 15, ty = tid >> 4;
  float acc[4][4] = {};
  int la_m = tid >> 2, la_k = (tid & 3) * 4;
  int lb_k = tid >> 4, lb_n = (tid & 15) * 4;
  for (int k0 = 0; k0 < 128; k0 += 16) {
    float4 a4 = *(const float4*)(A + (size_t)(i0 + la_m) * 128 + k0 + la_k);
    As[la_k + 0][la_m] = a4.x; As[la_k + 1][la_m] = a4.y;
    As[la_k + 2][la_m] = a4.z; As[la_k + 3][la_m] = a4.w;
    float4 b4 = *(const float4*)(Bp + (size_t)(k0 + lb_k) * 65536 + lb_n);
    *(float4*)&Bs[lb_k][lb_n] = b4;
    __syncthreads();
#pragma unroll
    for (int kk = 0; kk < 16; kk++) {
      float4 av = *(const float4*)&As[kk][ty * 4];
      float4 bv = *(const float4*)&Bs[kk][tx * 4];
      float a[4] = {av.x, av.y, av.z, av.w};
      float b[4] = {bv.x, bv.y, bv.z, bv.w};
#pragma unroll
      for (int i = 0; i < 4; i++)
#pragma unroll
        for (int j = 0; j < 4; j++) acc[i][j] += a[i] * b[j];
    }
    __syncthreads();
  }
#pragma unroll
  for (int i = 0; i < 4; i++) {
    float4 o;
    o.x = acc[i][0]; o.y = acc[i][1]; o.z = acc[i][2]; o.w = acc[i][3];
    *(float4*)(Cp + (size_t)(i0 + ty * 4 + i) * 8192 + tx * 4) = o;
  }
}

// ---------------- tt[(i,l), h*64+c] = sum_m ky[h,l,m] * t1[h,i,m,c]  (single batch) ----------------
__global__ __launch_bounds__(256) void k_t2(const float* __restrict__ KY,   // [8,128,128] this batch
                                            const float* __restrict__ T1,   // [8,128,128,64]
                                            float* __restrict__ TT) {       // [16384, 512]
  int h = blockIdx.z;
  int i = blockIdx.x;
  int l0 = blockIdx.y * 64;
  const float* A = KY + (size_t)h * 16384;
  const float* Bp = T1 + (size_t)h * 1048576 + (size_t)i * 8192;
  float* Cp = TT + (size_t)i * 65536 + h * 64;
  __shared__ float As[16][64];
  __shared__ float Bs[16][64];
  int tid = threadIdx.x, tx = tid & 15, ty = tid >> 4;
  float acc[4][4] = {};
  int la_m = tid >> 2, la_k = (tid & 3) * 4;
  int lb_k = tid >> 4, lb_n = (tid & 15) * 4;
  for (int k0 = 0; k0 < 128; k0 += 16) {
    float4 a4 = *(const float4*)(A + (size_t)(l0 + la_m) * 128 + k0 + la_k);
    As[la_k + 0][la_m] = a4.x; As[la_k + 1][la_m] = a4.y;
    As[la_k + 2][la_m] = a4.z; As[la_k + 3][la_m] = a4.w;
    float4 b4 = *(const float4*)(Bp + (size_t)(k0 + lb_k) * 64 + lb_n);
    *(float4*)&Bs[lb_k][lb_n] = b4;
    __syncthreads();
#pragma unroll
    for (int kk = 0; kk < 16; kk++) {
      float4 av = *(const float4*)&As[kk][ty * 4];
      float4 bv = *(const float4*)&Bs[kk][tx * 4];
      float a[4] = {av.x, av.y, av.z, av.w};
      float b[4] = {bv.x, bv.y, bv.z, bv.w};
#pragma unroll
      for (int ii = 0; ii < 4; ii++)
#pragma unroll
        for (int j = 0; j < 4; j++) acc[ii][j] += a[ii] * b[j];
    }
    __syncthreads();
  }
#pragma unroll
  for (int ii = 0; ii < 4; ii++) {
    float4 o;
    o.x = acc[ii][0]; o.y = acc[ii][1]; o.z = acc[ii][2]; o.w = acc[ii][3];
    *(float4*)(Cp + (size_t)(l0 + ty * 4 + ii) * 512 + tx * 4) = o;
  }
}

// ---------------- instance-norm stats per i over [l, 512] (single batch) ----------------
__global__ __launch_bounds__(256) void k_instat(const float* __restrict__ tt,
                                                float* __restrict__ mbuf,
                                                float* __restrict__ rbuf) {
  int i = blockIdx.x;
  const float* p = tt + (size_t)i * 65536;
  float s = 0, s2 = 0;
  for (int k = threadIdx.x; k < 65536; k += 256) {
    float v = p[k];
    s += v;
    s2 += v * v;
  }
  for (int off = 32; off > 0; off >>= 1) {
    s += __shfl_down(s, off, 64);
    s2 += __shfl_down(s2, off, 64);
  }
  __shared__ float ps[4], ps2[4];
  int w = threadIdx.x >> 6;
  if ((threadIdx.x & 63) == 0) { ps[w] = s; ps2[w] = s2; }
  __syncthreads();
  if (threadIdx.x == 0) {
    float S = ps[0] + ps[1] + ps[2] + ps[3];
    float S2 = ps2[0] + ps2[1] + ps2[2] + ps2[3];
    float mean = S * (1.f / 65536.f);
    float var = S2 * (1.f / 65536.f) - mean * mean;
    mbuf[i] = mean;
    rbuf[i] = rsqrtf(var + 1e-5f);
  }
}

__global__ __launch_bounds__(128) void k_colsum(const float* __restrict__ Wo1, float* __restrict__ s) {
  int n = threadIdx.x;
  float acc = 0;
  for (int k = 0; k < 512; k++) acc += Wo1[k * 128 + n];
  s[n] = acc;
}

extern "C" void kernel_launch(void* const* d_in, const int* in_sizes, int n_in,
                              void* d_out, int out_size, void* d_ws, size_t ws_size,
                              hipStream_t stream) {
  const float* u = (const float*)d_in[0];
  const float* pos_x = (const float*)d_in[1];
  const float* pos_y = (const float*)d_in[2];
  const float* ln_g = (const float*)d_in[3];
  const float* ln_b = (const float*)d_in[4];
  const float* Wv = (const float*)d_in[5];
  const float* Win = (const float*)d_in[6];
  const float* px_Win = (const float*)d_in[7];
  const float* px_g = (const float*)d_in[8];
  const float* px_b = (const float*)d_in[9];
  const float* px_W1 = (const float*)d_in[10];
  const float* px_b1 = (const float*)d_in[11];
  const float* px_W2 = (const float*)d_in[12];
  const float* px_b2 = (const float*)d_in[13];
  const float* py_Win = (const float*)d_in[14];
  const float* py_g = (const float*)d_in[15];
  const float* py_b = (const float*)d_in[16];
  const float* py_W1 = (const float*)d_in[17];
  const float* py_b1 = (const float*)d_in[18];
  const float* py_W2 = (const float*)d_in[19];
  const float* py_b2 = (const float*)d_in[20];
  const float* Wqk_x = (const float*)d_in[21];
  const float* Wqk_y = (const float*)d_in[22];
  const float* Wo1 = (const float*)d_in[23];
  const float* Wo2 = (const float*)d_in[24];
  float* out = (float*)d_out;

  // workspace layout (floats); total 29,590,656 floats = 113 MiB
  const size_t NEED = 29590656;
  if (ws_size < NEED * sizeof(float)) return;
  float* ws = (float*)d_ws;
  float* un   = ws;              // 8,388,608  [65536,128]
  float* buf1 = ws + 8388608;    // 8,388,608  v_b then tt_b [16384,512]
  float* t1b  = ws + 16777216;   // 8,388,608  t1_b [8,128,128,64]; later g1_b
  float* small = ws + 25165824;
  float* mun_x = small;             // 65,536 [512,128]
  float* mun_y = small + 65536;     // 65,536
  float* Wcx   = small + 131072;    // 16,384
  float* Wcy   = small + 147456;    // 16,384
  float* ux    = small + 163840;    // 32,768 [512,64]
  float* uy    = small + 196608;    // 32,768
  float* qk    = small + 229376;    // 1,572,864 [512,3072]
  float* qr    = small + 1802240;   // 786,432 [4,8,128,192]
  float* kr    = small + 2588672;   // 786,432
  float* kx    = small + 3375104;   // 524,288 [4,8,128,128]
  float* ky    = small + 3899392;   // 524,288
  float* mbuf  = small + 4423680;   // 512
  float* rbuf  = small + 4424192;   // 512
  float* scol  = small + 4424704;   // 128

  // Phase A: whole-tensor small stuff
  k_ln<<<ROWS, 128, 0, stream>>>(u, ln_g, ln_b, un);
  k_meanx<<<512, 128, 0, stream>>>(un, mun_x);
  k_meany<<<512, 128, 0, stream>>>(un, mun_y);
  // combined pooling weights: Wc = Win @ p*_Win  (mean commutes with linear maps)
  k_gemm<0><<<dim3(2, 2), 256, 0, stream>>>(Win, px_Win, Wcx, 128, 128, 128, 128, 128, 128,
                                            nullptr, nullptr, nullptr);
  k_gemm<0><<<dim3(2, 2), 256, 0, stream>>>(Win, py_Win, Wcy, 128, 128, 128, 128, 128, 128,
                                            nullptr, nullptr, nullptr);
  k_pool<<<512, 128, 0, stream>>>(mun_x, Wcx, px_g, px_b, px_W1, px_b1, px_W2, px_b2, ux);
  k_pool<<<512, 128, 0, stream>>>(mun_y, Wcy, py_g, py_b, py_W1, py_b1, py_W2, py_b2, uy);
  // x low-rank kernel
  k_gemm<0><<<dim3(48, 8), 256, 0, stream>>>(ux, Wqk_x, qk, 512, 3072, 64, 64, 3072, 3072,
                                             nullptr, nullptr, nullptr);
  k_rotary<<<512, 192, 0, stream>>>(qk, pos_x, qr, kr);
  k_qkt<<<dim3(2, 2, 32), 256, 0, stream>>>(qr, kr, kx);
  // y low-rank kernel
  k_gemm<0><<<dim3(48, 8), 256, 0, stream>>>(uy, Wqk_y, qk, 512, 3072, 64, 64, 3072, 3072,
                                             nullptr, nullptr, nullptr);
  k_rotary<<<512, 192, 0, stream>>>(qk, pos_y, qr, kr);
  k_qkt<<<dim3(2, 2, 32), 256, 0, stream>>>(qr, kr, ky);
  k_colsum<<<1, 128, 0, stream>>>(Wo1, scol);

  // Phase B: per-batch heavy path
  for (int b = 0; b < 4; b++) {
    const float* un_b = un + (size_t)b * 2097152;
    // v_b = un_b @ Wv   [16384,512]
    k_gemm<0><<<dim3(8, 256), 256, 0, stream>>>(un_b, Wv, buf1, 16384, HDIM, 128, 128, HDIM, HDIM,
                                                nullptr, nullptr, nullptr);
    // t1_b = kx_b contract v_b over j
    k_t1<<<dim3(128, 2, 8), 256, 0, stream>>>(kx + (size_t)b * 131072, buf1, t1b);
    // tt_b = ky_b contract t1_b over m  (overwrites buf1; v_b fully consumed by k_t1)
    k_t2<<<dim3(128, 2, 8), 256, 0, stream>>>(ky + (size_t)b * 131072, t1b, buf1);
    // instance-norm stats per i
    k_instat<<<128, 256, 0, stream>>>(buf1, mbuf + b * 128, rbuf + b * 128);
    // g1_b = gelu(instnorm(tt_b) @ Wo1), fused epilogue; g1_b aliases t1b
    float* g1b = t1b;
    k_gemm<1><<<dim3(2, 256), 256, 0, stream>>>(buf1, Wo1, g1b, 16384, 128, HDIM, HDIM, 128, 128,
                                                rbuf + b * 128, mbuf + b * 128, scol);
    // out_b = g1_b @ Wo2
    k_gemm<0><<<dim3(2, 256), 256, 0, stream>>>(g1b, Wo2, out + (size_t)b * 2097152, 16384, 128, 128,
                                                128, 128, 128, nullptr, nullptr, nullptr);
  }
}

// Round 3
// 664.790 us; speedup vs baseline: 1.6165x; 1.6165x over previous
//
#include <hip/hip_runtime.h>
#include <math.h>

#define ROWS 65536        // 4*128*128
#define HDIM 512          // 8*64
#define KDD 192

typedef __attribute__((ext_vector_type(8))) short bfrag;   // 8 bf16
typedef __attribute__((ext_vector_type(4))) float facc;    // 4 fp32

__device__ inline unsigned short bf16r(float x) {
  union { float f; unsigned u; } v; v.f = x;
  unsigned r = v.u + 0x7fffu + ((v.u >> 16) & 1u);
  return (unsigned short)(r >> 16);
}
__device__ inline float bf2f(unsigned short h) {
  union { unsigned u; float f; } v; v.u = ((unsigned)h) << 16; return v.f;
}

// ---------------- LayerNorm over last dim (128), bf16 output ----------------
__global__ __launch_bounds__(128) void k_ln(const float* __restrict__ x,
                                            const float* __restrict__ g,
                                            const float* __restrict__ bb,
                                            unsigned short* __restrict__ y) {
  int row = blockIdx.x;
  int t = threadIdx.x;
  float v = x[(size_t)row * 128 + t];
  float s = v, s2 = v * v;
  for (int off = 32; off > 0; off >>= 1) {
    s += __shfl_down(s, off, 64);
    s2 += __shfl_down(s2, off, 64);
  }
  __shared__ float ps[2], ps2[2];
  int wid = t >> 6, lane = t & 63;
  if (lane == 0) { ps[wid] = s; ps2[wid] = s2; }
  __syncthreads();
  float S = ps[0] + ps[1], S2 = ps2[0] + ps2[1];
  float mean = S * (1.f / 128.f);
  float var = S2 * (1.f / 128.f) - mean * mean;
  float r = rsqrtf(var + 1e-5f);
  y[(size_t)row * 128 + t] = bf16r((v - mean) * r * g[t] + bb[t]);
}

// ---------------- fp32 GEMM (small shapes only): C[M,N] = A[M,K] @ B[K,N] ----
__global__ __launch_bounds__(256) void k_gemm(const float* __restrict__ A,
                                              const float* __restrict__ Bm,
                                              float* __restrict__ C,
                                              int M, int N, int K,
                                              int lda, int ldb, int ldc) {
  __shared__ float As[16][64];
  __shared__ float Bs[16][64];
  int tid = threadIdx.x;
  int n0 = blockIdx.x * 64, m0 = blockIdx.y * 64;
  int tx = tid & 15, ty = tid >> 4;
  float acc[4][4] = {};
  int la_m = tid >> 2;
  int la_k = (tid & 3) * 4;
  int lb_k = tid >> 4;
  int lb_n = (tid & 15) * 4;
  for (int k0 = 0; k0 < K; k0 += 16) {
    float4 a4 = *(const float4*)(A + (size_t)(m0 + la_m) * lda + k0 + la_k);
    As[la_k + 0][la_m] = a4.x;
    As[la_k + 1][la_m] = a4.y;
    As[la_k + 2][la_m] = a4.z;
    As[la_k + 3][la_m] = a4.w;
    float4 b4 = *(const float4*)(Bm + (size_t)(k0 + lb_k) * ldb + n0 + lb_n);
    *(float4*)&Bs[lb_k][lb_n] = b4;
    __syncthreads();
#pragma unroll
    for (int kk = 0; kk < 16; kk++) {
      float4 av = *(const float4*)&As[kk][ty * 4];
      float4 bv = *(const float4*)&Bs[kk][tx * 4];
      float a[4] = {av.x, av.y, av.z, av.w};
      float b[4] = {bv.x, bv.y, bv.z, bv.w};
#pragma unroll
      for (int i = 0; i < 4; i++)
#pragma unroll
        for (int j = 0; j < 4; j++) acc[i][j] += a[i] * b[j];
    }
    __syncthreads();
  }
#pragma unroll
  for (int i = 0; i < 4; i++) {
    float4 o;
    o.x = acc[i][0]; o.y = acc[i][1]; o.z = acc[i][2]; o.w = acc[i][3];
    *(float4*)(C + (size_t)(m0 + ty * 4 + i) * ldc + n0 + tx * 4) = o;
  }
}

// ---------------- bf16 MFMA GEMM: C[M,N] = A[M,K] @ BT[N,K]^T ----------------
// 256 thr (4 waves), tile 64x64, K-step 32. EPI==1: instnorm+gelu, bf16 out.
template <int EPI, int OUTBF16>
__global__ __launch_bounds__(256) void k_mgemm(const unsigned short* __restrict__ A,
                                               const unsigned short* __restrict__ BT,
                                               void* __restrict__ C,
                                               int K, int ldc,
                                               const float* __restrict__ sb,
                                               const float* __restrict__ s2b,
                                               const float* __restrict__ sc) {
  __shared__ __align__(16) unsigned short Asl[64][40];
  __shared__ __align__(16) unsigned short Bsl[64][40];
  int tid = threadIdx.x;
  int m0 = blockIdx.y * 64, n0 = blockIdx.x * 64;
  int w = tid >> 6, lane = tid & 63, quad = lane >> 4, l16 = lane & 15;
  int srow = tid >> 2, schunk = (tid & 3) * 8;
  facc acc[4] = {{0,0,0,0},{0,0,0,0},{0,0,0,0},{0,0,0,0}};
  const unsigned short* Ap = A + (size_t)(m0 + srow) * K + schunk;
  const unsigned short* Bp = BT + (size_t)(n0 + srow) * K + schunk;
  for (int k0 = 0; k0 < K; k0 += 32) {
    uint4 av = *(const uint4*)(Ap + k0);
    uint4 bv = *(const uint4*)(Bp + k0);
    __syncthreads();
    *(uint4*)&Asl[srow][schunk] = av;
    *(uint4*)&Bsl[srow][schunk] = bv;
    __syncthreads();
    bfrag a = *(const bfrag*)&Asl[w * 16 + l16][quad * 8];
#pragma unroll
    for (int t = 0; t < 4; t++) {
      bfrag b = *(const bfrag*)&Bsl[t * 16 + l16][quad * 8];
      acc[t] = __builtin_amdgcn_mfma_f32_16x16x32_bf16(a, b, acc[t], 0, 0, 0);
    }
  }
  float mean = 0.f, rs = 0.f;
  if (EPI) {
    int i = m0 >> 7;
    float S = sb[i], S2 = s2b[i];
    mean = S * (1.f / 65536.f);
    float var = S2 * (1.f / 65536.f) - mean * mean;
    rs = rsqrtf(var + 1e-5f);
  }
#pragma unroll
  for (int t = 0; t < 4; t++) {
    int col = n0 + t * 16 + l16;
    float scv = EPI ? sc[col] : 0.f;
#pragma unroll
    for (int r = 0; r < 4; r++) {
      int row = m0 + w * 16 + quad * 4 + r;
      float vv = acc[t][r];
      if (EPI) {
        float val = (vv - mean * scv) * rs;
        vv = val * 0.5f * (1.f + erff(val * 0.70710678f));
      }
      if (OUTBF16)
        ((unsigned short*)C)[(size_t)row * ldc + col] = bf16r(vv);
      else
        ((float*)C)[(size_t)row * ldc + col] = vv;
    }
  }
}

// ---------------- means of un(bf16) over ny / nx ----------------
__global__ __launch_bounds__(128) void k_meanx(const unsigned short* __restrict__ un, float* __restrict__ mx) {
  int bi = blockIdx.x;  // b*128 + i
  int c = threadIdx.x;
  const unsigned short* p = un + (size_t)bi * 128 * 128 + c;
  float s = 0;
  for (int j = 0; j < 128; j++) s += bf2f(p[(size_t)j * 128]);
  mx[(size_t)bi * 128 + c] = s * (1.f / 128.f);
}
__global__ __launch_bounds__(128) void k_meany(const unsigned short* __restrict__ un, float* __restrict__ my) {
  int bj = blockIdx.x;  // b*128 + j
  int b = bj >> 7, j = bj & 127;
  const unsigned short* p = un + (size_t)b * 2097152 + (size_t)j * 128 + threadIdx.x;
  float s = 0;
  for (int i = 0; i < 128; i++) s += bf2f(p[(size_t)i * 16384]);
  my[(size_t)bj * 128 + threadIdx.x] = s * (1.f / 128.f);
}

// ---------------- pooling MLP: one row per block (W = Win@p_Win combined) ----
__global__ __launch_bounds__(128) void k_pool(const float* __restrict__ in,
                                              const float* __restrict__ Wc,
                                              const float* __restrict__ g,
                                              const float* __restrict__ bb,
                                              const float* __restrict__ W1,
                                              const float* __restrict__ b1,
                                              const float* __restrict__ W2,
                                              const float* __restrict__ b2,
                                              float* __restrict__ out) {
  int row = blockIdx.x;
  int t = threadIdx.x;
  __shared__ float xin[128], h1[128], h3[128];
  __shared__ float ps[2], ps2[2];
  xin[t] = in[(size_t)row * 128 + t];
  __syncthreads();
  float a = 0;
  for (int k = 0; k < 128; k++) a += xin[k] * Wc[k * 128 + t];
  float s = a, s2 = a * a;
  for (int off = 32; off > 0; off >>= 1) {
    s += __shfl_down(s, off, 64);
    s2 += __shfl_down(s2, off, 64);
  }
  if ((t & 63) == 0) { ps[t >> 6] = s; ps2[t >> 6] = s2; }
  __syncthreads();
  float S = ps[0] + ps[1], S2 = ps2[0] + ps2[1];
  float mean = S * (1.f / 128.f);
  float var = S2 * (1.f / 128.f) - mean * mean;
  float r = rsqrtf(var + 1e-5f);
  h1[t] = (a - mean) * r * g[t] + bb[t];
  __syncthreads();
  float u1 = b1[t], u2 = b1[t + 128];
  for (int k = 0; k < 128; k++) {
    float hv = h1[k];
    u1 += hv * W1[k * 256 + t];
    u2 += hv * W1[k * 256 + t + 128];
  }
  float ge = u1 * 0.5f * (1.f + erff(u1 * 0.70710678f));
  h3[t] = ge * u2;
  __syncthreads();
  if (t < 64) {
    float o = b2[t];
    for (int k = 0; k < 128; k++) o += h3[k] * W2[k * 64 + t];
    out[(size_t)row * 64 + t] = o;
  }
}

// ---------------- rotary ----------------
__global__ __launch_bounds__(192) void k_rotary(const float* __restrict__ qk,
                                                const float* __restrict__ pos,
                                                float* __restrict__ qr,
                                                float* __restrict__ kr) {
  int bn = blockIdx.x;  // b*128 + n
  int b = bn >> 7, n = bn & 127;
  int d = threadIdx.x;  // 0..191
  int fi = d % 96;
  float inv = expf(-logf(10000.f) * ((float)fi / 96.f));
  float f = pos[n] * 64.f * inv;
  float cs = cosf(f), sn = sinf(f);
  int partner = d < 96 ? d + 96 : d - 96;
  float sgn = d < 96 ? -1.f : 1.f;
  for (int h = 0; h < 8; h++) {
    float q = qk[(size_t)bn * 3072 + h * 192 + d];
    float qp = qk[(size_t)bn * 3072 + h * 192 + partner];
    float kx = qk[(size_t)bn * 3072 + 1536 + h * 192 + d];
    float kp = qk[(size_t)bn * 3072 + 1536 + h * 192 + partner];
    size_t o = ((size_t)(b * 8 + h) * 128 + n) * 192 + d;
    qr[o] = q * cs + sgn * qp * sn;
    kr[o] = kx * cs + sgn * kp * sn;
  }
}

// ---------------- batched Q@K^T per (b,h) ----------------
__global__ __launch_bounds__(256) void k_qkt(const float* __restrict__ Q,
                                             const float* __restrict__ Kt,
                                             float* __restrict__ C) {
  int bh = blockIdx.z;
  const float* Qb = Q + (size_t)bh * 128 * KDD;
  const float* Kb = Kt + (size_t)bh * 128 * KDD;
  float* Cb = C + (size_t)bh * 128 * 128;
  __shared__ float As[16][64];
  __shared__ float Bs[16][64];
  int tid = threadIdx.x;
  int i0 = blockIdx.y * 64, j0 = blockIdx.x * 64;
  int tx = tid & 15, ty = tid >> 4;
  float acc[4][4] = {};
  int l_m = tid >> 2, l_k = (tid & 3) * 4;
  for (int k0 = 0; k0 < KDD; k0 += 16) {
    float4 a4 = *(const float4*)(Qb + (size_t)(i0 + l_m) * KDD + k0 + l_k);
    As[l_k + 0][l_m] = a4.x; As[l_k + 1][l_m] = a4.y;
    As[l_k + 2][l_m] = a4.z; As[l_k + 3][l_m] = a4.w;
    float4 b4 = *(const float4*)(Kb + (size_t)(j0 + l_m) * KDD + k0 + l_k);
    Bs[l_k + 0][l_m] = b4.x; Bs[l_k + 1][l_m] = b4.y;
    Bs[l_k + 2][l_m] = b4.z; Bs[l_k + 3][l_m] = b4.w;
    __syncthreads();
#pragma unroll
    for (int kk = 0; kk < 16; kk++) {
      float4 av = *(const float4*)&As[kk][ty * 4];
      float4 bv = *(const float4*)&Bs[kk][tx * 4];
      float a[4] = {av.x, av.y, av.z, av.w};
      float b[4] = {bv.x, bv.y, bv.z, bv.w};
#pragma unroll
      for (int i = 0; i < 4; i++)
#pragma unroll
        for (int j = 0; j < 4; j++) acc[i][j] += a[i] * b[j];
    }
    __syncthreads();
  }
#pragma unroll
  for (int i = 0; i < 4; i++) {
    float4 o;
    o.x = acc[i][0]; o.y = acc[i][1]; o.z = acc[i][2]; o.w = acc[i][3];
    *(float4*)(Cb + (size_t)(i0 + ty * 4 + i) * 128 + j0 + tx * 4) = o;
  }
}

// ---------------- t1[h,i,m,c] = sum_j kx[h,i,j] * v_b[(j,m), h*64+c] ----------------
__global__ __launch_bounds__(256) void k_t1(const float* __restrict__ KX,
                                            const float* __restrict__ V,
                                            float* __restrict__ T1) {
  int h = blockIdx.z;
  int m = blockIdx.x;
  int i0 = blockIdx.y * 64;
  const float* A = KX + (size_t)h * 16384;
  const float* Bp = V + (size_t)m * 512 + h * 64;
  float* Cp = T1 + (size_t)h * 1048576 + (size_t)m * 64;
  __shared__ float As[16][64];
  __shared__ float Bs[16][64];
  int tid = threadIdx.x, tx = tid & 15, ty = tid >> 4;
  float acc[4][4] = {};
  int la_m = tid >> 2, la_k = (tid & 3) * 4;
  int lb_k = tid >> 4, lb_n = (tid & 15) * 4;
  for (int k0 = 0; k0 < 128; k0 += 16) {
    float4 a4 = *(const float4*)(A + (size_t)(i0 + la_m) * 128 + k0 + la_k);
    As[la_k + 0][la_m] = a4.x; As[la_k + 1][la_m] = a4.y;
    As[la_k + 2][la_m] = a4.z; As[la_k + 3][la_m] = a4.w;
    float4 b4 = *(const float4*)(Bp + (size_t)(k0 + lb_k) * 65536 + lb_n);
    *(float4*)&Bs[lb_k][lb_n] = b4;
    __syncthreads();
#pragma unroll
    for (int kk = 0; kk < 16; kk++) {
      float4 av = *(const float4*)&As[kk][ty * 4];
      float4 bv = *(const float4*)&Bs[kk][tx * 4];
      float a[4] = {av.x, av.y, av.z, av.w};
      float b[4] = {bv.x, bv.y, bv.z, bv.w};
#pragma unroll
      for (int i = 0; i < 4; i++)
#pragma unroll
        for (int j = 0; j < 4; j++) acc[i][j] += a[i] * b[j];
    }
    __syncthreads();
  }
#pragma unroll
  for (int i = 0; i < 4; i++) {
    float4 o;
    o.x = acc[i][0]; o.y = acc[i][1]; o.z = acc[i][2]; o.w = acc[i][3];
    *(float4*)(Cp + (size_t)(i0 + ty * 4 + i) * 8192 + tx * 4) = o;
  }
}

// ------- tt[(i,l), h*64+c] (bf16) = sum_m ky[h,l,m]*t1[h,i,m,c]; fused sum/sumsq atomics -------
__global__ __launch_bounds__(256) void k_t2(const float* __restrict__ KY,
                                            const float* __restrict__ T1,
                                            unsigned short* __restrict__ TT,
                                            float* __restrict__ sb,
                                            float* __restrict__ s2b) {
  int h = blockIdx.z;
  int i = blockIdx.x;
  int l0 = blockIdx.y * 64;
  const float* A = KY + (size_t)h * 16384;
  const float* Bp = T1 + (size_t)h * 1048576 + (size_t)i * 8192;
  unsigned short* Cp = TT + (size_t)i * 65536 + h * 64;
  __shared__ float As[16][64];
  __shared__ float Bs[16][64];
  int tid = threadIdx.x, tx = tid & 15, ty = tid >> 4;
  float acc[4][4] = {};
  int la_m = tid >> 2, la_k = (tid & 3) * 4;
  int lb_k = tid >> 4, lb_n = (tid & 15) * 4;
  for (int k0 = 0; k0 < 128; k0 += 16) {
    float4 a4 = *(const float4*)(A + (size_t)(l0 + la_m) * 128 + k0 + la_k);
    As[la_k + 0][la_m] = a4.x; As[la_k + 1][la_m] = a4.y;
    As[la_k + 2][la_m] = a4.z; As[la_k + 3][la_m] = a4.w;
    float4 b4 = *(const float4*)(Bp + (size_t)(k0 + lb_k) * 64 + lb_n);
    *(float4*)&Bs[lb_k][lb_n] = b4;
    __syncthreads();
#pragma unroll
    for (int kk = 0; kk < 16; kk++) {
      float4 av = *(const float4*)&As[kk][ty * 4];
      float4 bv = *(const float4*)&Bs[kk][tx * 4];
      float a[4] = {av.x, av.y, av.z, av.w};
      float b[4] = {bv.x, bv.y, bv.z, bv.w};
#pragma unroll
      for (int ii = 0; ii < 4; ii++)
#pragma unroll
        for (int j = 0; j < 4; j++) acc[ii][j] += a[ii] * b[j];
    }
    __syncthreads();
  }
  float s = 0, s2 = 0;
#pragma unroll
  for (int ii = 0; ii < 4; ii++) {
#pragma unroll
    for (int j = 0; j < 4; j++) { float vv = acc[ii][j]; s += vv; s2 += vv * vv; }
    unsigned h0 = bf16r(acc[ii][0]), h1 = bf16r(acc[ii][1]);
    unsigned h2 = bf16r(acc[ii][2]), h3 = bf16r(acc[ii][3]);
    uint2 pk;
    pk.x = h0 | (h1 << 16);
    pk.y = h2 | (h3 << 16);
    *(uint2*)(Cp + (size_t)(l0 + ty * 4 + ii) * 512 + tx * 4) = pk;
  }
  for (int off = 32; off > 0; off >>= 1) {
    s += __shfl_down(s, off, 64);
    s2 += __shfl_down(s2, off, 64);
  }
  __shared__ float ps[4], ps2[4];
  int w = tid >> 6;
  if ((tid & 63) == 0) { ps[w] = s; ps2[w] = s2; }
  __syncthreads();
  if (tid == 0) {
    atomicAdd(&sb[i], ps[0] + ps[1] + ps[2] + ps[3]);
    atomicAdd(&s2b[i], ps2[0] + ps2[1] + ps2[2] + ps2[3]);
  }
}

// colsum of bf16-rounded Wo1 (matches the bf16 operand used in the MFMA GEMM)
__global__ __launch_bounds__(128) void k_colsum(const float* __restrict__ Wo1, float* __restrict__ s) {
  int n = threadIdx.x;
  float acc = 0;
  for (int k = 0; k < 512; k++) acc += bf2f(bf16r(Wo1[k * 128 + n]));
  s[n] = acc;
}

// transpose fp32 [R,C] -> bf16 [C,R]
__global__ __launch_bounds__(256) void k_tr_bf(const float* __restrict__ in,
                                               unsigned short* __restrict__ out,
                                               int R, int Ccols) {
  int idx = blockIdx.x * 256 + threadIdx.x;
  if (idx >= R * Ccols) return;
  int r = idx / Ccols, c = idx % Ccols;
  out[(size_t)c * R + r] = bf16r(in[(size_t)r * Ccols + c]);
}

extern "C" void kernel_launch(void* const* d_in, const int* in_sizes, int n_in,
                              void* d_out, int out_size, void* d_ws, size_t ws_size,
                              hipStream_t stream) {
  const float* u = (const float*)d_in[0];
  const float* pos_x = (const float*)d_in[1];
  const float* pos_y = (const float*)d_in[2];
  const float* ln_g = (const float*)d_in[3];
  const float* ln_b = (const float*)d_in[4];
  const float* Wv = (const float*)d_in[5];
  const float* Win = (const float*)d_in[6];
  const float* px_Win = (const float*)d_in[7];
  const float* px_g = (const float*)d_in[8];
  const float* px_b = (const float*)d_in[9];
  const float* px_W1 = (const float*)d_in[10];
  const float* px_b1 = (const float*)d_in[11];
  const float* px_W2 = (const float*)d_in[12];
  const float* px_b2 = (const float*)d_in[13];
  const float* py_Win = (const float*)d_in[14];
  const float* py_g = (const float*)d_in[15];
  const float* py_b = (const float*)d_in[16];
  const float* py_W1 = (const float*)d_in[17];
  const float* py_b1 = (const float*)d_in[18];
  const float* py_W2 = (const float*)d_in[19];
  const float* py_b2 = (const float*)d_in[20];
  const float* Wqk_x = (const float*)d_in[21];
  const float* Wqk_y = (const float*)d_in[22];
  const float* Wo1 = (const float*)d_in[23];
  const float* Wo2 = (const float*)d_in[24];
  float* out = (float*)d_out;

  // workspace layout (float units); total 29,590,656 floats = 113 MiB
  const size_t NEED = 29590656;
  if (ws_size < NEED * sizeof(float)) return;
  float* ws = (float*)d_ws;
  unsigned short* un_bf = (unsigned short*)ws;     // [65536,128] bf16 (first 4,194,304 floats)
  float* extra = ws + 4194304;
  unsigned short* WvT  = (unsigned short*)(extra);           // [512,128] bf16
  unsigned short* Wo1T = (unsigned short*)(extra + 32768);   // [128,512] bf16
  unsigned short* Wo2T = (unsigned short*)(extra + 65536);   // [128,128] bf16
  float* sbuf  = extra + 73728;   // 512
  float* s2buf = extra + 74240;   // 512
  float* buf1 = ws + 8388608;     // v_b fp32 [16384,512] / tt_b bf16 [16384,512]
  float* t1b  = ws + 16777216;    // t1_b fp32 [8,128,128,64] / g1_b bf16 [16384,128]
  float* small = ws + 25165824;
  float* mun_x = small;             // 65,536
  float* mun_y = small + 65536;     // 65,536
  float* Wcx   = small + 131072;    // 16,384
  float* Wcy   = small + 147456;    // 16,384
  float* ux    = small + 163840;    // 32,768
  float* uy    = small + 196608;    // 32,768
  float* qk    = small + 229376;    // 1,572,864
  float* qr    = small + 1802240;   // 786,432
  float* kr    = small + 2588672;   // 786,432
  float* kx    = small + 3375104;   // 524,288
  float* ky    = small + 3899392;   // 524,288
  float* scol  = small + 4424704;   // 128

  // zero the instance-norm accumulators (ws is re-poisoned before every launch)
  hipMemsetAsync(sbuf, 0, 1024 * sizeof(float), stream);

  // Phase A
  k_ln<<<ROWS, 128, 0, stream>>>(u, ln_g, ln_b, un_bf);
  k_meanx<<<512, 128, 0, stream>>>(un_bf, mun_x);
  k_meany<<<512, 128, 0, stream>>>(un_bf, mun_y);
  k_tr_bf<<<(128 * 512 + 255) / 256, 256, 0, stream>>>(Wv, WvT, 128, 512);
  k_tr_bf<<<(512 * 128 + 255) / 256, 256, 0, stream>>>(Wo1, Wo1T, 512, 128);
  k_tr_bf<<<(128 * 128 + 255) / 256, 256, 0, stream>>>(Wo2, Wo2T, 128, 128);
  k_colsum<<<1, 128, 0, stream>>>(Wo1, scol);
  k_gemm<<<dim3(2, 2), 256, 0, stream>>>(Win, px_Win, Wcx, 128, 128, 128, 128, 128, 128);
  k_gemm<<<dim3(2, 2), 256, 0, stream>>>(Win, py_Win, Wcy, 128, 128, 128, 128, 128, 128);
  k_pool<<<512, 128, 0, stream>>>(mun_x, Wcx, px_g, px_b, px_W1, px_b1, px_W2, px_b2, ux);
  k_pool<<<512, 128, 0, stream>>>(mun_y, Wcy, py_g, py_b, py_W1, py_b1, py_W2, py_b2, uy);
  k_gemm<<<dim3(48, 8), 256, 0, stream>>>(ux, Wqk_x, qk, 512, 3072, 64, 64, 3072, 3072);
  k_rotary<<<512, 192, 0, stream>>>(qk, pos_x, qr, kr);
  k_qkt<<<dim3(2, 2, 32), 256, 0, stream>>>(qr, kr, kx);
  k_gemm<<<dim3(48, 8), 256, 0, stream>>>(uy, Wqk_y, qk, 512, 3072, 64, 64, 3072, 3072);
  k_rotary<<<512, 192, 0, stream>>>(qk, pos_y, qr, kr);
  k_qkt<<<dim3(2, 2, 32), 256, 0, stream>>>(qr, kr, ky);

  // Phase B: per-batch heavy path
  for (int b = 0; b < 4; b++) {
    const unsigned short* un_b = un_bf + (size_t)b * 2097152;
    // v_b = un_b @ Wv (MFMA bf16 -> fp32) [16384,512]
    k_mgemm<0, 0><<<dim3(8, 256), 256, 0, stream>>>(un_b, WvT, buf1, 128, HDIM,
                                                    nullptr, nullptr, nullptr);
    // t1_b = kx_b contract v_b over j (fp32)
    k_t1<<<dim3(128, 2, 8), 256, 0, stream>>>(kx + (size_t)b * 131072, buf1, t1b);
    // tt_b (bf16, overwrites buf1) + fused instnorm stats
    k_t2<<<dim3(128, 2, 8), 256, 0, stream>>>(ky + (size_t)b * 131072, t1b,
                                              (unsigned short*)buf1,
                                              sbuf + b * 128, s2buf + b * 128);
    // g1_b = gelu(instnorm(tt_b) @ Wo1) (MFMA, bf16 out, aliases t1b)
    unsigned short* g1b = (unsigned short*)t1b;
    k_mgemm<1, 1><<<dim3(2, 256), 256, 0, stream>>>((const unsigned short*)buf1, Wo1T, g1b,
                                                    HDIM, 128, sbuf + b * 128, s2buf + b * 128, scol);
    // out_b = g1_b @ Wo2 (MFMA -> fp32 final)
    k_mgemm<0, 0><<<dim3(2, 256), 256, 0, stream>>>(g1b, Wo2T, out + (size_t)b * 2097152,
                                                    128, 128, nullptr, nullptr, nullptr);
  }
}

// Round 4
// 445.761 us; speedup vs baseline: 2.4108x; 1.4914x over previous
//
#include <hip/hip_runtime.h>
#include <math.h>

#define ROWS 65536        // 4*128*128
#define HDIM 512          // 8*64
#define KDD 192

typedef __attribute__((ext_vector_type(8))) short bfrag;   // 8 bf16
typedef __attribute__((ext_vector_type(4))) float facc;    // 4 fp32
typedef unsigned short ushort_t;

__device__ inline unsigned short bf16r(float x) {
  union { float f; unsigned u; } v; v.f = x;
  unsigned r = v.u + 0x7fffu + ((v.u >> 16) & 1u);
  return (unsigned short)(r >> 16);
}
__device__ inline float bf2f(unsigned short h) {
  union { unsigned u; float f; } v; v.u = ((unsigned)h) << 16; return v.f;
}

// ---------------- LayerNorm over last dim (128), bf16 output ----------------
__global__ __launch_bounds__(128) void k_ln(const float* __restrict__ x,
                                            const float* __restrict__ g,
                                            const float* __restrict__ bb,
                                            unsigned short* __restrict__ y) {
  int row = blockIdx.x;
  int t = threadIdx.x;
  float v = x[(size_t)row * 128 + t];
  float s = v, s2 = v * v;
  for (int off = 32; off > 0; off >>= 1) {
    s += __shfl_down(s, off, 64);
    s2 += __shfl_down(s2, off, 64);
  }
  __shared__ float ps[2], ps2[2];
  int wid = t >> 6, lane = t & 63;
  if (lane == 0) { ps[wid] = s; ps2[wid] = s2; }
  __syncthreads();
  float S = ps[0] + ps[1], S2 = ps2[0] + ps2[1];
  float mean = S * (1.f / 128.f);
  float var = S2 * (1.f / 128.f) - mean * mean;
  float r = rsqrtf(var + 1e-5f);
  y[(size_t)row * 128 + t] = bf16r((v - mean) * r * g[t] + bb[t]);
}

// ---------------- fp32 GEMM (small shapes only): C[M,N] = A[M,K] @ B[K,N] ----
__global__ __launch_bounds__(256) void k_gemm(const float* __restrict__ A,
                                              const float* __restrict__ Bm,
                                              float* __restrict__ C,
                                              int M, int N, int K,
                                              int lda, int ldb, int ldc) {
  __shared__ float As[16][64];
  __shared__ float Bs[16][64];
  int tid = threadIdx.x;
  int n0 = blockIdx.x * 64, m0 = blockIdx.y * 64;
  int tx = tid & 15, ty = tid >> 4;
  float acc[4][4] = {};
  int la_m = tid >> 2;
  int la_k = (tid & 3) * 4;
  int lb_k = tid >> 4;
  int lb_n = (tid & 15) * 4;
  for (int k0 = 0; k0 < K; k0 += 16) {
    float4 a4 = *(const float4*)(A + (size_t)(m0 + la_m) * lda + k0 + la_k);
    As[la_k + 0][la_m] = a4.x;
    As[la_k + 1][la_m] = a4.y;
    As[la_k + 2][la_m] = a4.z;
    As[la_k + 3][la_m] = a4.w;
    float4 b4 = *(const float4*)(Bm + (size_t)(k0 + lb_k) * ldb + n0 + lb_n);
    *(float4*)&Bs[lb_k][lb_n] = b4;
    __syncthreads();
#pragma unroll
    for (int kk = 0; kk < 16; kk++) {
      float4 av = *(const float4*)&As[kk][ty * 4];
      float4 bv = *(const float4*)&Bs[kk][tx * 4];
      float a[4] = {av.x, av.y, av.z, av.w};
      float b[4] = {bv.x, bv.y, bv.z, bv.w};
#pragma unroll
      for (int i = 0; i < 4; i++)
#pragma unroll
        for (int j = 0; j < 4; j++) acc[i][j] += a[i] * b[j];
    }
    __syncthreads();
  }
#pragma unroll
  for (int i = 0; i < 4; i++) {
    float4 o;
    o.x = acc[i][0]; o.y = acc[i][1]; o.z = acc[i][2]; o.w = acc[i][3];
    *(float4*)(C + (size_t)(m0 + ty * 4 + i) * ldc + n0 + tx * 4) = o;
  }
}

// ---------------- bf16 MFMA GEMM: C[M,N] = A[M,K] @ BT[N,K]^T ----------------
// 256 thr (4 waves), tile 64x64, K-step 32. EPI==1: instnorm+gelu epilogue.
template <int EPI, int OUTBF16>
__global__ __launch_bounds__(256) void k_mgemm(const unsigned short* __restrict__ A,
                                               const unsigned short* __restrict__ BT,
                                               void* __restrict__ C,
                                               int K, int ldc,
                                               const float* __restrict__ sb,
                                               const float* __restrict__ s2b,
                                               const float* __restrict__ sc) {
  __shared__ __align__(16) unsigned short Asl[64][40];
  __shared__ __align__(16) unsigned short Bsl[64][40];
  int tid = threadIdx.x;
  int m0 = blockIdx.y * 64, n0 = blockIdx.x * 64;
  int w = tid >> 6, lane = tid & 63, quad = lane >> 4, l16 = lane & 15;
  int srow = tid >> 2, schunk = (tid & 3) * 8;
  facc acc[4] = {{0,0,0,0},{0,0,0,0},{0,0,0,0},{0,0,0,0}};
  const unsigned short* Ap = A + (size_t)(m0 + srow) * K + schunk;
  const unsigned short* Bp = BT + (size_t)(n0 + srow) * K + schunk;
  for (int k0 = 0; k0 < K; k0 += 32) {
    uint4 av = *(const uint4*)(Ap + k0);
    uint4 bv = *(const uint4*)(Bp + k0);
    __syncthreads();
    *(uint4*)&Asl[srow][schunk] = av;
    *(uint4*)&Bsl[srow][schunk] = bv;
    __syncthreads();
    bfrag a = *(const bfrag*)&Asl[w * 16 + l16][quad * 8];
#pragma unroll
    for (int t = 0; t < 4; t++) {
      bfrag b = *(const bfrag*)&Bsl[t * 16 + l16][quad * 8];
      acc[t] = __builtin_amdgcn_mfma_f32_16x16x32_bf16(a, b, acc[t], 0, 0, 0);
    }
  }
  float mean = 0.f, rs = 0.f;
  if (EPI) {
    int i = m0 >> 7;
    float S = sb[i], S2 = s2b[i];
    mean = S * (1.f / 65536.f);
    float var = S2 * (1.f / 65536.f) - mean * mean;
    rs = rsqrtf(var + 1e-5f);
  }
#pragma unroll
  for (int t = 0; t < 4; t++) {
    int col = n0 + t * 16 + l16;
    float scv = EPI ? sc[col] : 0.f;
#pragma unroll
    for (int r = 0; r < 4; r++) {
      int row = m0 + w * 16 + quad * 4 + r;
      float vv = acc[t][r];
      if (EPI) {
        float val = (vv - mean * scv) * rs;
        vv = val * 0.5f * (1.f + erff(val * 0.70710678f));
      }
      if (OUTBF16)
        ((unsigned short*)C)[(size_t)row * ldc + col] = bf16r(vv);
      else
        ((float*)C)[(size_t)row * ldc + col] = vv;
    }
  }
}

// ---- transpose v[(b,j,m),(h,c)] bf16 -> vB[b][h][c][m][j] bf16 ----
__global__ __launch_bounds__(256) void k_trv(const unsigned short* __restrict__ v,
                                             unsigned short* __restrict__ vB) {
  int x = blockIdx.x;
  int jt = x & 1;
  int m = (x >> 1) & 127;
  int h = (x >> 8) & 7;
  int b = x >> 11;
  __shared__ unsigned short L[64][72];
  int tid = threadIdx.x;
  int jj = tid >> 2, ck = (tid & 3) * 16;
  const unsigned short* src = v + ((size_t)b * 16384 + (size_t)(jt * 64 + jj) * 128 + m) * 512 + h * 64 + ck;
  uint4 d0 = *(const uint4*)src;
  uint4 d1 = *(const uint4*)(src + 8);
  *(uint4*)&L[jj][ck] = d0;
  *(uint4*)&L[jj][ck + 8] = d1;
  __syncthreads();
  int c = tid >> 2, jk = (tid & 3) * 16;
  unsigned short tmp[16];
#pragma unroll
  for (int q = 0; q < 16; q++) tmp[q] = L[jk + q][c];
  unsigned short* dst = vB + (((size_t)(b * 8 + h) * 64 + c) * 128 + m) * 128 + jt * 64 + jk;
  *(uint4*)dst = *(uint4*)&tmp[0];
  *(uint4*)(dst + 8) = *(uint4*)&tmp[8];
}

// ---- t1x[bh][i][c][m] = sum_j kx[bh][i][j] * vB[bh][c][m][j]  (MFMA) ----
__global__ __launch_bounds__(256) void k_t1m(const unsigned short* __restrict__ kxall,
                                             const unsigned short* __restrict__ vB,
                                             unsigned short* __restrict__ t1x) {
  int bh = blockIdx.z;
  int c = blockIdx.y >> 1, m0 = (blockIdx.y & 1) * 64;
  int i0 = blockIdx.x * 64;
  const unsigned short* A = kxall + (size_t)bh * 16384;
  const unsigned short* B = vB + (size_t)bh * 1048576 + (size_t)c * 16384 + (size_t)m0 * 128;
  __shared__ __align__(16) unsigned short Asl[64][40];
  __shared__ __align__(16) unsigned short Bsl[64][40];
  int tid = threadIdx.x;
  int w = tid >> 6, lane = tid & 63, quad = lane >> 4, l16 = lane & 15;
  int srow = tid >> 2, schunk = (tid & 3) * 8;
  facc acc[4] = {{0,0,0,0},{0,0,0,0},{0,0,0,0},{0,0,0,0}};
  const unsigned short* Ap = A + (size_t)(i0 + srow) * 128 + schunk;
  const unsigned short* Bp = B + (size_t)srow * 128 + schunk;
  for (int k0 = 0; k0 < 128; k0 += 32) {
    uint4 av = *(const uint4*)(Ap + k0);
    uint4 bv = *(const uint4*)(Bp + k0);
    __syncthreads();
    *(uint4*)&Asl[srow][schunk] = av;
    *(uint4*)&Bsl[srow][schunk] = bv;
    __syncthreads();
    bfrag a = *(const bfrag*)&Asl[w * 16 + l16][quad * 8];
#pragma unroll
    for (int t = 0; t < 4; t++) {
      bfrag b = *(const bfrag*)&Bsl[t * 16 + l16][quad * 8];
      acc[t] = __builtin_amdgcn_mfma_f32_16x16x32_bf16(a, b, acc[t], 0, 0, 0);
    }
  }
#pragma unroll
  for (int t = 0; t < 4; t++) {
    int m = m0 + t * 16 + l16;
#pragma unroll
    for (int r = 0; r < 4; r++) {
      int i = i0 + w * 16 + quad * 4 + r;
      t1x[((size_t)(bh * 128 + i) * 64 + c) * 128 + m] = bf16r(acc[t][r]);
    }
  }
}

// ---- tt[(b,i,l),(h,c)] = sum_m ky[bh][l][m] * t1x[bh][i][c][m]; fused stats ----
__global__ __launch_bounds__(256) void k_t2m(const unsigned short* __restrict__ kyall,
                                             const unsigned short* __restrict__ t1x,
                                             unsigned short* __restrict__ TT,
                                             float* __restrict__ sb,
                                             float* __restrict__ s2b) {
  int bh = blockIdx.z;
  int b = bh >> 3, h = bh & 7;
  int i = blockIdx.y;
  int l0 = blockIdx.x * 64;
  const unsigned short* A = kyall + (size_t)bh * 16384;
  const unsigned short* B = t1x + ((size_t)(bh * 128 + i)) * 8192;
  __shared__ __align__(16) unsigned short Asl[64][40];
  __shared__ __align__(16) unsigned short Bsl[64][40];
  int tid = threadIdx.x;
  int w = tid >> 6, lane = tid & 63, quad = lane >> 4, l16 = lane & 15;
  int srow = tid >> 2, schunk = (tid & 3) * 8;
  facc acc[4] = {{0,0,0,0},{0,0,0,0},{0,0,0,0},{0,0,0,0}};
  const unsigned short* Ap = A + (size_t)(l0 + srow) * 128 + schunk;
  const unsigned short* Bp = B + (size_t)srow * 128 + schunk;
  for (int k0 = 0; k0 < 128; k0 += 32) {
    uint4 av = *(const uint4*)(Ap + k0);
    uint4 bv = *(const uint4*)(Bp + k0);
    __syncthreads();
    *(uint4*)&Asl[srow][schunk] = av;
    *(uint4*)&Bsl[srow][schunk] = bv;
    __syncthreads();
    bfrag a = *(const bfrag*)&Asl[w * 16 + l16][quad * 8];
#pragma unroll
    for (int t = 0; t < 4; t++) {
      bfrag b = *(const bfrag*)&Bsl[t * 16 + l16][quad * 8];
      acc[t] = __builtin_amdgcn_mfma_f32_16x16x32_bf16(a, b, acc[t], 0, 0, 0);
    }
  }
  float s = 0.f, s2 = 0.f;
#pragma unroll
  for (int t = 0; t < 4; t++) {
    int cc = t * 16 + l16;
#pragma unroll
    for (int r = 0; r < 4; r++) {
      int l = l0 + w * 16 + quad * 4 + r;
      float vv = acc[t][r];
      unsigned short hb = bf16r(vv);
      float vq = bf2f(hb);
      s += vq; s2 += vq * vq;
      TT[((size_t)b * 16384 + (size_t)i * 128 + l) * 512 + h * 64 + cc] = hb;
    }
  }
  for (int off = 32; off > 0; off >>= 1) {
    s += __shfl_down(s, off, 64);
    s2 += __shfl_down(s2, off, 64);
  }
  __shared__ float ps[4], ps2[4];
  if ((tid & 63) == 0) { ps[w] = s; ps2[w] = s2; }
  __syncthreads();
  if (tid == 0) {
    atomicAdd(&sb[b * 128 + i], ps[0] + ps[1] + ps[2] + ps[3]);
    atomicAdd(&s2b[b * 128 + i], ps2[0] + ps2[1] + ps2[2] + ps2[3]);
  }
}

// ---------------- means of un(bf16) over ny / nx ----------------
__global__ __launch_bounds__(128) void k_meanx(const unsigned short* __restrict__ un, float* __restrict__ mx) {
  int bi = blockIdx.x;
  int c = threadIdx.x;
  const unsigned short* p = un + (size_t)bi * 128 * 128 + c;
  float s = 0;
  for (int j = 0; j < 128; j++) s += bf2f(p[(size_t)j * 128]);
  mx[(size_t)bi * 128 + c] = s * (1.f / 128.f);
}
__global__ __launch_bounds__(128) void k_meany(const unsigned short* __restrict__ un, float* __restrict__ my) {
  int bj = blockIdx.x;
  int b = bj >> 7, j = bj & 127;
  const unsigned short* p = un + (size_t)b * 2097152 + (size_t)j * 128 + threadIdx.x;
  float s = 0;
  for (int i = 0; i < 128; i++) s += bf2f(p[(size_t)i * 16384]);
  my[(size_t)bj * 128 + threadIdx.x] = s * (1.f / 128.f);
}

// ---------------- pooling MLP ----------------
__global__ __launch_bounds__(128) void k_pool(const float* __restrict__ in,
                                              const float* __restrict__ Wc,
                                              const float* __restrict__ g,
                                              const float* __restrict__ bb,
                                              const float* __restrict__ W1,
                                              const float* __restrict__ b1,
                                              const float* __restrict__ W2,
                                              const float* __restrict__ b2,
                                              float* __restrict__ out) {
  int row = blockIdx.x;
  int t = threadIdx.x;
  __shared__ float xin[128], h1[128], h3[128];
  __shared__ float ps[2], ps2[2];
  xin[t] = in[(size_t)row * 128 + t];
  __syncthreads();
  float a = 0;
  for (int k = 0; k < 128; k++) a += xin[k] * Wc[k * 128 + t];
  float s = a, s2 = a * a;
  for (int off = 32; off > 0; off >>= 1) {
    s += __shfl_down(s, off, 64);
    s2 += __shfl_down(s2, off, 64);
  }
  if ((t & 63) == 0) { ps[t >> 6] = s; ps2[t >> 6] = s2; }
  __syncthreads();
  float S = ps[0] + ps[1], S2 = ps2[0] + ps2[1];
  float mean = S * (1.f / 128.f);
  float var = S2 * (1.f / 128.f) - mean * mean;
  float r = rsqrtf(var + 1e-5f);
  h1[t] = (a - mean) * r * g[t] + bb[t];
  __syncthreads();
  float u1 = b1[t], u2 = b1[t + 128];
  for (int k = 0; k < 128; k++) {
    float hv = h1[k];
    u1 += hv * W1[k * 256 + t];
    u2 += hv * W1[k * 256 + t + 128];
  }
  float ge = u1 * 0.5f * (1.f + erff(u1 * 0.70710678f));
  h3[t] = ge * u2;
  __syncthreads();
  if (t < 64) {
    float o = b2[t];
    for (int k = 0; k < 128; k++) o += h3[k] * W2[k * 64 + t];
    out[(size_t)row * 64 + t] = o;
  }
}

// ---------------- rotary ----------------
__global__ __launch_bounds__(192) void k_rotary(const float* __restrict__ qk,
                                                const float* __restrict__ pos,
                                                float* __restrict__ qr,
                                                float* __restrict__ kr) {
  int bn = blockIdx.x;
  int b = bn >> 7, n = bn & 127;
  int d = threadIdx.x;
  int fi = d % 96;
  float inv = expf(-logf(10000.f) * ((float)fi / 96.f));
  float f = pos[n] * 64.f * inv;
  float cs = cosf(f), sn = sinf(f);
  int partner = d < 96 ? d + 96 : d - 96;
  float sgn = d < 96 ? -1.f : 1.f;
  for (int h = 0; h < 8; h++) {
    float q = qk[(size_t)bn * 3072 + h * 192 + d];
    float qp = qk[(size_t)bn * 3072 + h * 192 + partner];
    float kx = qk[(size_t)bn * 3072 + 1536 + h * 192 + d];
    float kp = qk[(size_t)bn * 3072 + 1536 + h * 192 + partner];
    size_t o = ((size_t)(b * 8 + h) * 128 + n) * 192 + d;
    qr[o] = q * cs + sgn * qp * sn;
    kr[o] = kx * cs + sgn * kp * sn;
  }
}

// ---------------- batched Q@K^T per (b,h), bf16 output ----------------
__global__ __launch_bounds__(256) void k_qkt(const float* __restrict__ Q,
                                             const float* __restrict__ Kt,
                                             unsigned short* __restrict__ C) {
  int bh = blockIdx.z;
  const float* Qb = Q + (size_t)bh * 128 * KDD;
  const float* Kb = Kt + (size_t)bh * 128 * KDD;
  unsigned short* Cb = C + (size_t)bh * 128 * 128;
  __shared__ float As[16][64];
  __shared__ float Bs[16][64];
  int tid = threadIdx.x;
  int i0 = blockIdx.y * 64, j0 = blockIdx.x * 64;
  int tx = tid & 15, ty = tid >> 4;
  float acc[4][4] = {};
  int l_m = tid >> 2, l_k = (tid & 3) * 4;
  for (int k0 = 0; k0 < KDD; k0 += 16) {
    float4 a4 = *(const float4*)(Qb + (size_t)(i0 + l_m) * KDD + k0 + l_k);
    As[l_k + 0][l_m] = a4.x; As[l_k + 1][l_m] = a4.y;
    As[l_k + 2][l_m] = a4.z; As[l_k + 3][l_m] = a4.w;
    float4 b4 = *(const float4*)(Kb + (size_t)(j0 + l_m) * KDD + k0 + l_k);
    Bs[l_k + 0][l_m] = b4.x; Bs[l_k + 1][l_m] = b4.y;
    Bs[l_k + 2][l_m] = b4.z; Bs[l_k + 3][l_m] = b4.w;
    __syncthreads();
#pragma unroll
    for (int kk = 0; kk < 16; kk++) {
      float4 av = *(const float4*)&As[kk][ty * 4];
      float4 bv = *(const float4*)&Bs[kk][tx * 4];
      float a[4] = {av.x, av.y, av.z, av.w};
      float b[4] = {bv.x, bv.y, bv.z, bv.w};
#pragma unroll
      for (int i = 0; i < 4; i++)
#pragma unroll
        for (int j = 0; j < 4; j++) acc[i][j] += a[i] * b[j];
    }
    __syncthreads();
  }
#pragma unroll
  for (int i = 0; i < 4; i++) {
    unsigned h0 = bf16r(acc[i][0]), h1 = bf16r(acc[i][1]);
    unsigned h2 = bf16r(acc[i][2]), h3 = bf16r(acc[i][3]);
    uint2 pk;
    pk.x = h0 | (h1 << 16);
    pk.y = h2 | (h3 << 16);
    *(uint2*)(Cb + (size_t)(i0 + ty * 4 + i) * 128 + j0 + tx * 4) = pk;
  }
}

__global__ __launch_bounds__(128) void k_colsum(const float* __restrict__ Wo1, float* __restrict__ s) {
  int n = threadIdx.x;
  float acc = 0;
  for (int k = 0; k < 512; k++) acc += bf2f(bf16r(Wo1[k * 128 + n]));
  s[n] = acc;
}

// transpose fp32 [R,C] -> bf16 [C,R]
__global__ __launch_bounds__(256) void k_tr_bf(const float* __restrict__ in,
                                               unsigned short* __restrict__ out,
                                               int R, int Ccols) {
  int idx = blockIdx.x * 256 + threadIdx.x;
  if (idx >= R * Ccols) return;
  int r = idx / Ccols, c = idx % Ccols;
  out[(size_t)c * R + r] = bf16r(in[(size_t)r * Ccols + c]);
}

extern "C" void kernel_launch(void* const* d_in, const int* in_sizes, int n_in,
                              void* d_out, int out_size, void* d_ws, size_t ws_size,
                              hipStream_t stream) {
  const float* u = (const float*)d_in[0];
  const float* pos_x = (const float*)d_in[1];
  const float* pos_y = (const float*)d_in[2];
  const float* ln_g = (const float*)d_in[3];
  const float* ln_b = (const float*)d_in[4];
  const float* Wv = (const float*)d_in[5];
  const float* Win = (const float*)d_in[6];
  const float* px_Win = (const float*)d_in[7];
  const float* px_g = (const float*)d_in[8];
  const float* px_b = (const float*)d_in[9];
  const float* px_W1 = (const float*)d_in[10];
  const float* px_b1 = (const float*)d_in[11];
  const float* px_W2 = (const float*)d_in[12];
  const float* px_b2 = (const float*)d_in[13];
  const float* py_Win = (const float*)d_in[14];
  const float* py_g = (const float*)d_in[15];
  const float* py_b = (const float*)d_in[16];
  const float* py_W1 = (const float*)d_in[17];
  const float* py_b1 = (const float*)d_in[18];
  const float* py_W2 = (const float*)d_in[19];
  const float* py_b2 = (const float*)d_in[20];
  const float* Wqk_x = (const float*)d_in[21];
  const float* Wqk_y = (const float*)d_in[22];
  const float* Wo1 = (const float*)d_in[23];
  const float* Wo2 = (const float*)d_in[24];
  float* out = (float*)d_out;

  // workspace layout (float units); ~167 MB (ws is 256 MiB per harness fill size)
  const size_t NEED = 41723008;
  if (ws_size < NEED * sizeof(float)) return;
  float* ws = (float*)d_ws;
  unsigned short* un_bf = (unsigned short*)ws;              // [65536,128] bf16; later g1
  unsigned short* g1    = un_bf;
  unsigned short* vbuf  = (unsigned short*)(ws + 4194304);  // v bf16 [65536,512]; later t1x
  unsigned short* t1x   = vbuf;
  unsigned short* vB    = (unsigned short*)(ws + 20971520); // vB[b][h][c][m][j]; later tt
  unsigned short* tt    = vB;
  float* small = ws + 37748736;
  float* mun_x = small;                              // 65,536
  float* mun_y = small + 65536;                      // 65,536
  float* Wcx   = small + 131072;                     // 16,384
  float* Wcy   = small + 147456;                     // 16,384
  float* ux    = small + 163840;                     // 32,768
  float* uy    = small + 196608;                     // 32,768
  float* qk    = small + 229376;                     // 1,572,864
  float* qr    = small + 1802240;                    // 786,432
  float* kr    = small + 2588672;                    // 786,432
  unsigned short* kx_bf = (unsigned short*)(small + 3375104);  // 524,288 el
  unsigned short* ky_bf = (unsigned short*)(small + 3637248);  // 524,288 el
  unsigned short* WvT   = (unsigned short*)(small + 3899392);  // 65,536 el
  unsigned short* Wo1T  = (unsigned short*)(small + 3932160);  // 65,536 el
  unsigned short* Wo2T  = (unsigned short*)(small + 3964928);  // 16,384 el
  float* sbuf  = small + 3973120;                    // 512
  float* s2buf = small + 3973632;                    // 512
  float* scol  = small + 3974144;                    // 128

  hipMemsetAsync(sbuf, 0, 1024 * sizeof(float), stream);

  // Phase A
  k_ln<<<ROWS, 128, 0, stream>>>(u, ln_g, ln_b, un_bf);
  k_meanx<<<512, 128, 0, stream>>>(un_bf, mun_x);
  k_meany<<<512, 128, 0, stream>>>(un_bf, mun_y);
  k_tr_bf<<<(128 * 512 + 255) / 256, 256, 0, stream>>>(Wv, WvT, 128, 512);
  k_tr_bf<<<(512 * 128 + 255) / 256, 256, 0, stream>>>(Wo1, Wo1T, 512, 128);
  k_tr_bf<<<(128 * 128 + 255) / 256, 256, 0, stream>>>(Wo2, Wo2T, 128, 128);
  k_colsum<<<1, 128, 0, stream>>>(Wo1, scol);
  k_gemm<<<dim3(2, 2), 256, 0, stream>>>(Win, px_Win, Wcx, 128, 128, 128, 128, 128, 128);
  k_gemm<<<dim3(2, 2), 256, 0, stream>>>(Win, py_Win, Wcy, 128, 128, 128, 128, 128, 128);
  k_pool<<<512, 128, 0, stream>>>(mun_x, Wcx, px_g, px_b, px_W1, px_b1, px_W2, px_b2, ux);
  k_pool<<<512, 128, 0, stream>>>(mun_y, Wcy, py_g, py_b, py_W1, py_b1, py_W2, py_b2, uy);
  k_gemm<<<dim3(48, 8), 256, 0, stream>>>(ux, Wqk_x, qk, 512, 3072, 64, 64, 3072, 3072);
  k_rotary<<<512, 192, 0, stream>>>(qk, pos_x, qr, kr);
  k_qkt<<<dim3(2, 2, 32), 256, 0, stream>>>(qr, kr, kx_bf);
  k_gemm<<<dim3(48, 8), 256, 0, stream>>>(uy, Wqk_y, qk, 512, 3072, 64, 64, 3072, 3072);
  k_rotary<<<512, 192, 0, stream>>>(qk, pos_y, qr, kr);
  k_qkt<<<dim3(2, 2, 32), 256, 0, stream>>>(qr, kr, ky_bf);

  // Phase B: whole-tensor heavy path
  // v = un @ Wv (bf16 out) [65536,512]
  k_mgemm<0, 1><<<dim3(8, 1024), 256, 0, stream>>>(un_bf, WvT, vbuf, 128, HDIM,
                                                   nullptr, nullptr, nullptr);
  // vB[b][h][c][m][j] = v[(b,j,m)][(h,c)]
  k_trv<<<8192, 256, 0, stream>>>(vbuf, vB);
  // t1x[bh][i][c][m] = kx @ vB  (t1x aliases vbuf; vbuf dead after k_trv)
  k_t1m<<<dim3(2, 128, 32), 256, 0, stream>>>(kx_bf, vB, t1x);
  // tt[(b,i,l),(h,c)] = ky @ t1x + fused instnorm stats (tt aliases vB)
  k_t2m<<<dim3(2, 128, 32), 256, 0, stream>>>(ky_bf, t1x, tt, sbuf, s2buf);
  // g1 = gelu(instnorm(tt) @ Wo1)  (g1 aliases un_bf)
  k_mgemm<1, 1><<<dim3(2, 1024), 256, 0, stream>>>(tt, Wo1T, g1, HDIM, 128,
                                                   sbuf, s2buf, scol);
  // out = g1 @ Wo2
  k_mgemm<0, 0><<<dim3(2, 1024), 256, 0, stream>>>(g1, Wo2T, out, 128, 128,
                                                   nullptr, nullptr, nullptr);
}

// Round 5
// 440.063 us; speedup vs baseline: 2.4420x; 1.0129x over previous
//
#include <hip/hip_runtime.h>
#include <math.h>

#define ROWS 65536        // 4*128*128
#define HDIM 512          // 8*64
#define KDD 192

typedef __attribute__((ext_vector_type(8))) short bfrag;   // 8 bf16
typedef __attribute__((ext_vector_type(4))) float facc;    // 4 fp32
typedef unsigned short ushort_t;

__device__ inline unsigned short bf16r(float x) {
  union { float f; unsigned u; } v; v.f = x;
  unsigned r = v.u + 0x7fffu + ((v.u >> 16) & 1u);
  return (unsigned short)(r >> 16);
}
__device__ inline float bf2f(unsigned short h) {
  union { unsigned u; float f; } v; v.u = ((unsigned)h) << 16; return v.f;
}

// ---------------- LayerNorm over last dim (128), bf16 output ----------------
__global__ __launch_bounds__(128) void k_ln(const float* __restrict__ x,
                                            const float* __restrict__ g,
                                            const float* __restrict__ bb,
                                            unsigned short* __restrict__ y) {
  int row = blockIdx.x;
  int t = threadIdx.x;
  float v = x[(size_t)row * 128 + t];
  float s = v, s2 = v * v;
  for (int off = 32; off > 0; off >>= 1) {
    s += __shfl_down(s, off, 64);
    s2 += __shfl_down(s2, off, 64);
  }
  __shared__ float ps[2], ps2[2];
  int wid = t >> 6, lane = t & 63;
  if (lane == 0) { ps[wid] = s; ps2[wid] = s2; }
  __syncthreads();
  float S = ps[0] + ps[1], S2 = ps2[0] + ps2[1];
  float mean = S * (1.f / 128.f);
  float var = S2 * (1.f / 128.f) - mean * mean;
  float r = rsqrtf(var + 1e-5f);
  y[(size_t)row * 128 + t] = bf16r((v - mean) * r * g[t] + bb[t]);
}

// ---------------- fp32 GEMM (small shapes only) ----------------
__global__ __launch_bounds__(256) void k_gemm(const float* __restrict__ A,
                                              const float* __restrict__ Bm,
                                              float* __restrict__ C,
                                              int M, int N, int K,
                                              int lda, int ldb, int ldc) {
  __shared__ float As[16][64];
  __shared__ float Bs[16][64];
  int tid = threadIdx.x;
  int n0 = blockIdx.x * 64, m0 = blockIdx.y * 64;
  int tx = tid & 15, ty = tid >> 4;
  float acc[4][4] = {};
  int la_m = tid >> 2;
  int la_k = (tid & 3) * 4;
  int lb_k = tid >> 4;
  int lb_n = (tid & 15) * 4;
  for (int k0 = 0; k0 < K; k0 += 16) {
    float4 a4 = *(const float4*)(A + (size_t)(m0 + la_m) * lda + k0 + la_k);
    As[la_k + 0][la_m] = a4.x;
    As[la_k + 1][la_m] = a4.y;
    As[la_k + 2][la_m] = a4.z;
    As[la_k + 3][la_m] = a4.w;
    float4 b4 = *(const float4*)(Bm + (size_t)(k0 + lb_k) * ldb + n0 + lb_n);
    *(float4*)&Bs[lb_k][lb_n] = b4;
    __syncthreads();
#pragma unroll
    for (int kk = 0; kk < 16; kk++) {
      float4 av = *(const float4*)&As[kk][ty * 4];
      float4 bv = *(const float4*)&Bs[kk][tx * 4];
      float a[4] = {av.x, av.y, av.z, av.w};
      float b[4] = {bv.x, bv.y, bv.z, bv.w};
#pragma unroll
      for (int i = 0; i < 4; i++)
#pragma unroll
        for (int j = 0; j < 4; j++) acc[i][j] += a[i] * b[j];
    }
    __syncthreads();
  }
#pragma unroll
  for (int i = 0; i < 4; i++) {
    float4 o;
    o.x = acc[i][0]; o.y = acc[i][1]; o.z = acc[i][2]; o.w = acc[i][3];
    *(float4*)(C + (size_t)(m0 + ty * 4 + i) * ldc + n0 + tx * 4) = o;
  }
}

// ---- single-stage K=128 bf16 MFMA GEMM: C[M,N](bf16) = A[M,128] @ BT[N,128]^T ----
__global__ __launch_bounds__(256) void k_mg128(const unsigned short* __restrict__ A,
                                               const unsigned short* __restrict__ BT,
                                               unsigned short* __restrict__ C,
                                               int ldc) {
  int n0 = blockIdx.x * 64, m0 = blockIdx.y * 64;
  __shared__ __align__(16) unsigned short Asl[64][136];
  __shared__ __align__(16) unsigned short Bsl[64][136];
  int tid = threadIdx.x;
  int w = tid >> 6, lane = tid & 63, quad = lane >> 4, l16 = lane & 15;
  int srow = tid >> 2, sch = (tid & 3) * 32;
  const unsigned short* Ap = A + (size_t)(m0 + srow) * 128 + sch;
  const unsigned short* Bp = BT + (size_t)(n0 + srow) * 128 + sch;
#pragma unroll
  for (int q = 0; q < 4; q++) {
    *(uint4*)&Asl[srow][sch + q * 8] = *(const uint4*)(Ap + q * 8);
    *(uint4*)&Bsl[srow][sch + q * 8] = *(const uint4*)(Bp + q * 8);
  }
  __syncthreads();
  facc acc[4] = {{0,0,0,0},{0,0,0,0},{0,0,0,0},{0,0,0,0}};
#pragma unroll
  for (int k0 = 0; k0 < 4; k0++) {
    bfrag a = *(const bfrag*)&Asl[w * 16 + l16][k0 * 32 + quad * 8];
#pragma unroll
    for (int nt = 0; nt < 4; nt++) {
      bfrag b = *(const bfrag*)&Bsl[nt * 16 + l16][k0 * 32 + quad * 8];
      acc[nt] = __builtin_amdgcn_mfma_f32_16x16x32_bf16(a, b, acc[nt], 0, 0, 0);
    }
  }
#pragma unroll
  for (int nt = 0; nt < 4; nt++) {
    int col = n0 + nt * 16 + l16;
#pragma unroll
    for (int r = 0; r < 4; r++) {
      int row = m0 + w * 16 + quad * 4 + r;
      C[(size_t)row * ldc + col] = bf16r(acc[nt][r]);
    }
  }
}

// ---- transpose v[(b,j,m),(h,c)] bf16 -> vB[b][h][c][m][j] bf16 ----
__global__ __launch_bounds__(256) void k_trv(const unsigned short* __restrict__ v,
                                             unsigned short* __restrict__ vB) {
  int x = blockIdx.x;
  int jt = x & 1;
  int m = (x >> 1) & 127;
  int h = (x >> 8) & 7;
  int b = x >> 11;
  __shared__ unsigned short L[64][72];
  int tid = threadIdx.x;
  int jj = tid >> 2, ck = (tid & 3) * 16;
  const unsigned short* src = v + ((size_t)b * 16384 + (size_t)(jt * 64 + jj) * 128 + m) * 512 + h * 64 + ck;
  uint4 d0 = *(const uint4*)src;
  uint4 d1 = *(const uint4*)(src + 8);
  *(uint4*)&L[jj][ck] = d0;
  *(uint4*)&L[jj][ck + 8] = d1;
  __syncthreads();
  int c = tid >> 2, jk = (tid & 3) * 16;
  unsigned short tmp[16];
#pragma unroll
  for (int q = 0; q < 16; q++) tmp[q] = L[jk + q][c];
  unsigned short* dst = vB + (((size_t)(b * 8 + h) * 64 + c) * 128 + m) * 128 + jt * 64 + jk;
  *(uint4*)dst = *(uint4*)&tmp[0];
  *(uint4*)(dst + 8) = *(uint4*)&tmp[8];
}

// ---- t1x[bh][i][c][m] = sum_j kx[bh][i][j] * vB[bh][c][m][j]  (single-stage K=128) ----
__global__ __launch_bounds__(256) void k_t1m(const unsigned short* __restrict__ kxall,
                                             const unsigned short* __restrict__ vB,
                                             unsigned short* __restrict__ t1x) {
  int bh = blockIdx.z;
  int c = blockIdx.y >> 1, m0 = (blockIdx.y & 1) * 64;
  int i0 = blockIdx.x * 64;
  const unsigned short* A = kxall + (size_t)bh * 16384 + (size_t)i0 * 128;
  const unsigned short* B = vB + (size_t)bh * 1048576 + (size_t)c * 16384 + (size_t)m0 * 128;
  __shared__ __align__(16) unsigned short Asl[64][136];
  __shared__ __align__(16) unsigned short Bsl[64][136];
  int tid = threadIdx.x;
  int w = tid >> 6, lane = tid & 63, quad = lane >> 4, l16 = lane & 15;
  int srow = tid >> 2, sch = (tid & 3) * 32;
#pragma unroll
  for (int q = 0; q < 4; q++) {
    *(uint4*)&Asl[srow][sch + q * 8] = *(const uint4*)(A + (size_t)srow * 128 + sch + q * 8);
    *(uint4*)&Bsl[srow][sch + q * 8] = *(const uint4*)(B + (size_t)srow * 128 + sch + q * 8);
  }
  __syncthreads();
  facc acc[4] = {{0,0,0,0},{0,0,0,0},{0,0,0,0},{0,0,0,0}};
#pragma unroll
  for (int k0 = 0; k0 < 4; k0++) {
    bfrag a = *(const bfrag*)&Asl[w * 16 + l16][k0 * 32 + quad * 8];
#pragma unroll
    for (int nt = 0; nt < 4; nt++) {
      bfrag b = *(const bfrag*)&Bsl[nt * 16 + l16][k0 * 32 + quad * 8];
      acc[nt] = __builtin_amdgcn_mfma_f32_16x16x32_bf16(a, b, acc[nt], 0, 0, 0);
    }
  }
#pragma unroll
  for (int nt = 0; nt < 4; nt++) {
    int m = m0 + nt * 16 + l16;
#pragma unroll
    for (int r = 0; r < 4; r++) {
      int i = i0 + w * 16 + quad * 4 + r;
      t1x[((size_t)(bh * 128 + i) * 64 + c) * 128 + m] = bf16r(acc[nt][r]);
    }
  }
}

// ---- tt[(b,i,l),(h,c)] = sum_m ky[bh][l][m] * t1x[bh][i][c][m]; fused stats ----
__global__ __launch_bounds__(256) void k_t2m(const unsigned short* __restrict__ kyall,
                                             const unsigned short* __restrict__ t1x,
                                             unsigned short* __restrict__ TT,
                                             float* __restrict__ sb,
                                             float* __restrict__ s2b) {
  int bh = blockIdx.z;
  int b = bh >> 3, h = bh & 7;
  int i = blockIdx.y;
  int l0 = blockIdx.x * 64;
  const unsigned short* A = kyall + (size_t)bh * 16384 + (size_t)l0 * 128;
  const unsigned short* B = t1x + ((size_t)(bh * 128 + i)) * 8192;
  __shared__ __align__(16) unsigned short Asl[64][136];
  __shared__ __align__(16) unsigned short Bsl[64][136];
  int tid = threadIdx.x;
  int w = tid >> 6, lane = tid & 63, quad = lane >> 4, l16 = lane & 15;
  int srow = tid >> 2, sch = (tid & 3) * 32;
#pragma unroll
  for (int q = 0; q < 4; q++) {
    *(uint4*)&Asl[srow][sch + q * 8] = *(const uint4*)(A + (size_t)srow * 128 + sch + q * 8);
    *(uint4*)&Bsl[srow][sch + q * 8] = *(const uint4*)(B + (size_t)srow * 128 + sch + q * 8);
  }
  __syncthreads();
  facc acc[4] = {{0,0,0,0},{0,0,0,0},{0,0,0,0},{0,0,0,0}};
#pragma unroll
  for (int k0 = 0; k0 < 4; k0++) {
    bfrag a = *(const bfrag*)&Asl[w * 16 + l16][k0 * 32 + quad * 8];
#pragma unroll
    for (int nt = 0; nt < 4; nt++) {
      bfrag b = *(const bfrag*)&Bsl[nt * 16 + l16][k0 * 32 + quad * 8];
      acc[nt] = __builtin_amdgcn_mfma_f32_16x16x32_bf16(a, b, acc[nt], 0, 0, 0);
    }
  }
  float s = 0.f, s2 = 0.f;
#pragma unroll
  for (int nt = 0; nt < 4; nt++) {
    int cc = nt * 16 + l16;
#pragma unroll
    for (int r = 0; r < 4; r++) {
      int l = l0 + w * 16 + quad * 4 + r;
      unsigned short hb = bf16r(acc[nt][r]);
      float vq = bf2f(hb);
      s += vq; s2 += vq * vq;
      TT[((size_t)b * 16384 + (size_t)i * 128 + l) * 512 + h * 64 + cc] = hb;
    }
  }
  for (int off = 32; off > 0; off >>= 1) {
    s += __shfl_down(s, off, 64);
    s2 += __shfl_down(s2, off, 64);
  }
  __shared__ float ps[4], ps2[4];
  if ((tid & 63) == 0) { ps[w] = s; ps2[w] = s2; }
  __syncthreads();
  if (tid == 0) {
    atomicAdd(&sb[b * 128 + i], ps[0] + ps[1] + ps[2] + ps[3]);
    atomicAdd(&s2b[b * 128 + i], ps2[0] + ps2[1] + ps2[2] + ps2[3]);
  }
}

// ---- fused tail: out[m,:] = gelu(instnorm(tt)[m,:] @ Wo1) @ Wo2 ----
// grid 1024 (M-tile 64), block 256.
__global__ __launch_bounds__(256) void k_tail(const unsigned short* __restrict__ TT,
                                              const unsigned short* __restrict__ Wo1T,
                                              const unsigned short* __restrict__ Wo2T,
                                              float* __restrict__ out,
                                              const float* __restrict__ sb,
                                              const float* __restrict__ s2b,
                                              const float* __restrict__ sc) {
  int m0 = blockIdx.x * 64;
  int bi = blockIdx.x >> 1;
  __shared__ __align__(16) unsigned short As[64][136];
  __shared__ __align__(16) unsigned short Bs[128][136];
  __shared__ __align__(16) unsigned short G[64][136];
  int tid = threadIdx.x;
  int w = tid >> 6, lane = tid & 63, quad = lane >> 4, l16 = lane & 15;
  int srow = tid >> 2, sch = (tid & 3) * 32;
  int bn = tid >> 1, bkh = (tid & 1) * 64;
  facc acc1[8] = {{0,0,0,0},{0,0,0,0},{0,0,0,0},{0,0,0,0},
                  {0,0,0,0},{0,0,0,0},{0,0,0,0},{0,0,0,0}};
  for (int kc = 0; kc < 4; kc++) {
    __syncthreads();
#pragma unroll
    for (int q = 0; q < 4; q++)
      *(uint4*)&As[srow][sch + q * 8] =
          *(const uint4*)(TT + (size_t)(m0 + srow) * 512 + kc * 128 + sch + q * 8);
#pragma unroll
    for (int q = 0; q < 8; q++)
      *(uint4*)&Bs[bn][bkh + q * 8] =
          *(const uint4*)(Wo1T + (size_t)bn * 512 + kc * 128 + bkh + q * 8);
    __syncthreads();
#pragma unroll
    for (int k0 = 0; k0 < 4; k0++) {
      bfrag a = *(const bfrag*)&As[w * 16 + l16][k0 * 32 + quad * 8];
#pragma unroll
      for (int nt = 0; nt < 8; nt++) {
        bfrag b = *(const bfrag*)&Bs[nt * 16 + l16][k0 * 32 + quad * 8];
        acc1[nt] = __builtin_amdgcn_mfma_f32_16x16x32_bf16(a, b, acc1[nt], 0, 0, 0);
      }
    }
  }
  // instnorm + gelu epilogue -> G (bf16 g1 tile)
  float S = sb[bi], S2 = s2b[bi];
  float mean = S * (1.f / 65536.f);
  float var = S2 * (1.f / 65536.f) - mean * mean;
  float rs = rsqrtf(var + 1e-5f);
#pragma unroll
  for (int nt = 0; nt < 8; nt++) {
    int col = nt * 16 + l16;
    float scn = sc[col];
#pragma unroll
    for (int r = 0; r < 4; r++) {
      int row = w * 16 + quad * 4 + r;
      float val = (acc1[nt][r] - mean * scn) * rs;
      float ge = val * 0.5f * (1.f + erff(val * 0.70710678f));
      G[row][col] = bf16r(ge);
    }
  }
  __syncthreads();
  // restage Bs with Wo2T [128][128]
#pragma unroll
  for (int q = 0; q < 8; q++)
    *(uint4*)&Bs[bn][bkh + q * 8] = *(const uint4*)(Wo2T + (size_t)bn * 128 + bkh + q * 8);
  __syncthreads();
  facc acc2[8] = {{0,0,0,0},{0,0,0,0},{0,0,0,0},{0,0,0,0},
                  {0,0,0,0},{0,0,0,0},{0,0,0,0},{0,0,0,0}};
#pragma unroll
  for (int k0 = 0; k0 < 4; k0++) {
    bfrag a = *(const bfrag*)&G[w * 16 + l16][k0 * 32 + quad * 8];
#pragma unroll
    for (int nt = 0; nt < 8; nt++) {
      bfrag b = *(const bfrag*)&Bs[nt * 16 + l16][k0 * 32 + quad * 8];
      acc2[nt] = __builtin_amdgcn_mfma_f32_16x16x32_bf16(a, b, acc2[nt], 0, 0, 0);
    }
  }
#pragma unroll
  for (int nt = 0; nt < 8; nt++) {
    int col = nt * 16 + l16;
#pragma unroll
    for (int r = 0; r < 4; r++) {
      int row = m0 + w * 16 + quad * 4 + r;
      out[(size_t)row * 128 + col] = acc2[nt][r];
    }
  }
}

// ---------------- means of un(bf16) over ny / nx ----------------
__global__ __launch_bounds__(128) void k_meanx(const unsigned short* __restrict__ un, float* __restrict__ mx) {
  int bi = blockIdx.x;
  int c = threadIdx.x;
  const unsigned short* p = un + (size_t)bi * 128 * 128 + c;
  float s = 0;
  for (int j = 0; j < 128; j++) s += bf2f(p[(size_t)j * 128]);
  mx[(size_t)bi * 128 + c] = s * (1.f / 128.f);
}
__global__ __launch_bounds__(128) void k_meany(const unsigned short* __restrict__ un, float* __restrict__ my) {
  int bj = blockIdx.x;
  int b = bj >> 7, j = bj & 127;
  const unsigned short* p = un + (size_t)b * 2097152 + (size_t)j * 128 + threadIdx.x;
  float s = 0;
  for (int i = 0; i < 128; i++) s += bf2f(p[(size_t)i * 16384]);
  my[(size_t)bj * 128 + threadIdx.x] = s * (1.f / 128.f);
}

// ---------------- pooling MLP ----------------
__global__ __launch_bounds__(128) void k_pool(const float* __restrict__ in,
                                              const float* __restrict__ Wc,
                                              const float* __restrict__ g,
                                              const float* __restrict__ bb,
                                              const float* __restrict__ W1,
                                              const float* __restrict__ b1,
                                              const float* __restrict__ W2,
                                              const float* __restrict__ b2,
                                              float* __restrict__ out) {
  int row = blockIdx.x;
  int t = threadIdx.x;
  __shared__ float xin[128], h1[128], h3[128];
  __shared__ float ps[2], ps2[2];
  xin[t] = in[(size_t)row * 128 + t];
  __syncthreads();
  float a = 0;
  for (int k = 0; k < 128; k++) a += xin[k] * Wc[k * 128 + t];
  float s = a, s2 = a * a;
  for (int off = 32; off > 0; off >>= 1) {
    s += __shfl_down(s, off, 64);
    s2 += __shfl_down(s2, off, 64);
  }
  if ((t & 63) == 0) { ps[t >> 6] = s; ps2[t >> 6] = s2; }
  __syncthreads();
  float S = ps[0] + ps[1], S2 = ps2[0] + ps2[1];
  float mean = S * (1.f / 128.f);
  float var = S2 * (1.f / 128.f) - mean * mean;
  float r = rsqrtf(var + 1e-5f);
  h1[t] = (a - mean) * r * g[t] + bb[t];
  __syncthreads();
  float u1 = b1[t], u2 = b1[t + 128];
  for (int k = 0; k < 128; k++) {
    float hv = h1[k];
    u1 += hv * W1[k * 256 + t];
    u2 += hv * W1[k * 256 + t + 128];
  }
  float ge = u1 * 0.5f * (1.f + erff(u1 * 0.70710678f));
  h3[t] = ge * u2;
  __syncthreads();
  if (t < 64) {
    float o = b2[t];
    for (int k = 0; k < 128; k++) o += h3[k] * W2[k * 64 + t];
    out[(size_t)row * 64 + t] = o;
  }
}

// ---------------- rotary ----------------
__global__ __launch_bounds__(192) void k_rotary(const float* __restrict__ qk,
                                                const float* __restrict__ pos,
                                                float* __restrict__ qr,
                                                float* __restrict__ kr) {
  int bn = blockIdx.x;
  int b = bn >> 7, n = bn & 127;
  int d = threadIdx.x;
  int fi = d % 96;
  float inv = expf(-logf(10000.f) * ((float)fi / 96.f));
  float f = pos[n] * 64.f * inv;
  float cs = cosf(f), sn = sinf(f);
  int partner = d < 96 ? d + 96 : d - 96;
  float sgn = d < 96 ? -1.f : 1.f;
  for (int h = 0; h < 8; h++) {
    float q = qk[(size_t)bn * 3072 + h * 192 + d];
    float qp = qk[(size_t)bn * 3072 + h * 192 + partner];
    float kx = qk[(size_t)bn * 3072 + 1536 + h * 192 + d];
    float kp = qk[(size_t)bn * 3072 + 1536 + h * 192 + partner];
    size_t o = ((size_t)(b * 8 + h) * 128 + n) * 192 + d;
    qr[o] = q * cs + sgn * qp * sn;
    kr[o] = kx * cs + sgn * kp * sn;
  }
}

// ---------------- batched Q@K^T per (b,h), bf16 output ----------------
__global__ __launch_bounds__(256) void k_qkt(const float* __restrict__ Q,
                                             const float* __restrict__ Kt,
                                             unsigned short* __restrict__ C) {
  int bh = blockIdx.z;
  const float* Qb = Q + (size_t)bh * 128 * KDD;
  const float* Kb = Kt + (size_t)bh * 128 * KDD;
  unsigned short* Cb = C + (size_t)bh * 128 * 128;
  __shared__ float As[16][64];
  __shared__ float Bs[16][64];
  int tid = threadIdx.x;
  int i0 = blockIdx.y * 64, j0 = blockIdx.x * 64;
  int tx = tid & 15, ty = tid >> 4;
  float acc[4][4] = {};
  int l_m = tid >> 2, l_k = (tid & 3) * 4;
  for (int k0 = 0; k0 < KDD; k0 += 16) {
    float4 a4 = *(const float4*)(Qb + (size_t)(i0 + l_m) * KDD + k0 + l_k);
    As[l_k + 0][l_m] = a4.x; As[l_k + 1][l_m] = a4.y;
    As[l_k + 2][l_m] = a4.z; As[l_k + 3][l_m] = a4.w;
    float4 b4 = *(const float4*)(Kb + (size_t)(j0 + l_m) * KDD + k0 + l_k);
    Bs[l_k + 0][l_m] = b4.x; Bs[l_k + 1][l_m] = b4.y;
    Bs[l_k + 2][l_m] = b4.z; Bs[l_k + 3][l_m] = b4.w;
    __syncthreads();
#pragma unroll
    for (int kk = 0; kk < 16; kk++) {
      float4 av = *(const float4*)&As[kk][ty * 4];
      float4 bv = *(const float4*)&Bs[kk][tx * 4];
      float a[4] = {av.x, av.y, av.z, av.w};
      float b[4] = {bv.x, bv.y, bv.z, bv.w};
#pragma unroll
      for (int i = 0; i < 4; i++)
#pragma unroll
        for (int j = 0; j < 4; j++) acc[i][j] += a[i] * b[j];
    }
    __syncthreads();
  }
#pragma unroll
  for (int i = 0; i < 4; i++) {
    unsigned h0 = bf16r(acc[i][0]), h1 = bf16r(acc[i][1]);
    unsigned h2 = bf16r(acc[i][2]), h3 = bf16r(acc[i][3]);
    uint2 pk;
    pk.x = h0 | (h1 << 16);
    pk.y = h2 | (h3 << 16);
    *(uint2*)(Cb + (size_t)(i0 + ty * 4 + i) * 128 + j0 + tx * 4) = pk;
  }
}

__global__ __launch_bounds__(128) void k_colsum(const float* __restrict__ Wo1, float* __restrict__ s) {
  int n = threadIdx.x;
  float acc = 0;
  for (int k = 0; k < 512; k++) acc += bf2f(bf16r(Wo1[k * 128 + n]));
  s[n] = acc;
}

// transpose fp32 [R,C] -> bf16 [C,R]
__global__ __launch_bounds__(256) void k_tr_bf(const float* __restrict__ in,
                                               unsigned short* __restrict__ out,
                                               int R, int Ccols) {
  int idx = blockIdx.x * 256 + threadIdx.x;
  if (idx >= R * Ccols) return;
  int r = idx / Ccols, c = idx % Ccols;
  out[(size_t)c * R + r] = bf16r(in[(size_t)r * Ccols + c]);
}

extern "C" void kernel_launch(void* const* d_in, const int* in_sizes, int n_in,
                              void* d_out, int out_size, void* d_ws, size_t ws_size,
                              hipStream_t stream) {
  const float* u = (const float*)d_in[0];
  const float* pos_x = (const float*)d_in[1];
  const float* pos_y = (const float*)d_in[2];
  const float* ln_g = (const float*)d_in[3];
  const float* ln_b = (const float*)d_in[4];
  const float* Wv = (const float*)d_in[5];
  const float* Win = (const float*)d_in[6];
  const float* px_Win = (const float*)d_in[7];
  const float* px_g = (const float*)d_in[8];
  const float* px_b = (const float*)d_in[9];
  const float* px_W1 = (const float*)d_in[10];
  const float* px_b1 = (const float*)d_in[11];
  const float* px_W2 = (const float*)d_in[12];
  const float* px_b2 = (const float*)d_in[13];
  const float* py_Win = (const float*)d_in[14];
  const float* py_g = (const float*)d_in[15];
  const float* py_b = (const float*)d_in[16];
  const float* py_W1 = (const float*)d_in[17];
  const float* py_b1 = (const float*)d_in[18];
  const float* py_W2 = (const float*)d_in[19];
  const float* py_b2 = (const float*)d_in[20];
  const float* Wqk_x = (const float*)d_in[21];
  const float* Wqk_y = (const float*)d_in[22];
  const float* Wo1 = (const float*)d_in[23];
  const float* Wo2 = (const float*)d_in[24];
  float* out = (float*)d_out;

  const size_t NEED = 41723008;
  if (ws_size < NEED * sizeof(float)) return;
  float* ws = (float*)d_ws;
  unsigned short* un_bf = (unsigned short*)ws;              // [65536,128] bf16
  unsigned short* vbuf  = (unsigned short*)(ws + 4194304);  // v bf16 [65536,512]; later t1x
  unsigned short* t1x   = vbuf;
  unsigned short* vB    = (unsigned short*)(ws + 20971520); // vB[b][h][c][m][j]; later tt
  unsigned short* tt    = vB;
  float* small = ws + 37748736;
  float* mun_x = small;                              // 65,536
  float* mun_y = small + 65536;                      // 65,536
  float* Wcx   = small + 131072;                     // 16,384
  float* Wcy   = small + 147456;                     // 16,384
  float* ux    = small + 163840;                     // 32,768
  float* uy    = small + 196608;                     // 32,768
  float* qk    = small + 229376;                     // 1,572,864
  float* qr    = small + 1802240;                    // 786,432
  float* kr    = small + 2588672;                    // 786,432
  unsigned short* kx_bf = (unsigned short*)(small + 3375104);  // 524,288 el
  unsigned short* ky_bf = (unsigned short*)(small + 3637248);  // 524,288 el
  unsigned short* WvT   = (unsigned short*)(small + 3899392);  // 65,536 el
  unsigned short* Wo1T  = (unsigned short*)(small + 3932160);  // 65,536 el
  unsigned short* Wo2T  = (unsigned short*)(small + 3964928);  // 16,384 el
  float* sbuf  = small + 3973120;                    // 512
  float* s2buf = small + 3973632;                    // 512
  float* scol  = small + 3974144;                    // 128

  hipMemsetAsync(sbuf, 0, 1024 * sizeof(float), stream);

  // Phase A
  k_ln<<<ROWS, 128, 0, stream>>>(u, ln_g, ln_b, un_bf);
  k_meanx<<<512, 128, 0, stream>>>(un_bf, mun_x);
  k_meany<<<512, 128, 0, stream>>>(un_bf, mun_y);
  k_tr_bf<<<(128 * 512 + 255) / 256, 256, 0, stream>>>(Wv, WvT, 128, 512);
  k_tr_bf<<<(512 * 128 + 255) / 256, 256, 0, stream>>>(Wo1, Wo1T, 512, 128);
  k_tr_bf<<<(128 * 128 + 255) / 256, 256, 0, stream>>>(Wo2, Wo2T, 128, 128);
  k_colsum<<<1, 128, 0, stream>>>(Wo1, scol);
  k_gemm<<<dim3(2, 2), 256, 0, stream>>>(Win, px_Win, Wcx, 128, 128, 128, 128, 128, 128);
  k_gemm<<<dim3(2, 2), 256, 0, stream>>>(Win, py_Win, Wcy, 128, 128, 128, 128, 128, 128);
  k_pool<<<512, 128, 0, stream>>>(mun_x, Wcx, px_g, px_b, px_W1, px_b1, px_W2, px_b2, ux);
  k_pool<<<512, 128, 0, stream>>>(mun_y, Wcy, py_g, py_b, py_W1, py_b1, py_W2, py_b2, uy);
  k_gemm<<<dim3(48, 8), 256, 0, stream>>>(ux, Wqk_x, qk, 512, 3072, 64, 64, 3072, 3072);
  k_rotary<<<512, 192, 0, stream>>>(qk, pos_x, qr, kr);
  k_qkt<<<dim3(2, 2, 32), 256, 0, stream>>>(qr, kr, kx_bf);
  k_gemm<<<dim3(48, 8), 256, 0, stream>>>(uy, Wqk_y, qk, 512, 3072, 64, 64, 3072, 3072);
  k_rotary<<<512, 192, 0, stream>>>(qk, pos_y, qr, kr);
  k_qkt<<<dim3(2, 2, 32), 256, 0, stream>>>(qr, kr, ky_bf);

  // Phase B
  // v = un @ Wv (bf16 out) [65536,512]
  k_mg128<<<dim3(8, 1024), 256, 0, stream>>>(un_bf, WvT, vbuf, HDIM);
  // vB[b][h][c][m][j]
  k_trv<<<8192, 256, 0, stream>>>(vbuf, vB);
  // t1x = kx @ vB  (aliases vbuf)
  k_t1m<<<dim3(2, 128, 32), 256, 0, stream>>>(kx_bf, vB, t1x);
  // tt = ky @ t1x + fused instnorm stats (aliases vB)
  k_t2m<<<dim3(2, 128, 32), 256, 0, stream>>>(ky_bf, t1x, tt, sbuf, s2buf);
  // out = gelu(instnorm(tt) @ Wo1) @ Wo2  (fused tail)
  k_tail<<<1024, 256, 0, stream>>>(tt, Wo1T, Wo2T, out, sbuf, s2buf, scol);
}

// Round 6
// 349.943 us; speedup vs baseline: 3.0709x; 1.2575x over previous
//
#include <hip/hip_runtime.h>
#include <math.h>

#define ROWS 65536        // 4*128*128
#define KDD 192

typedef __attribute__((ext_vector_type(8))) short bfrag;   // 8 bf16
typedef __attribute__((ext_vector_type(4))) float facc;    // 4 fp32

__device__ inline unsigned short bf16r(float x) {
  union { float f; unsigned u; } v; v.f = x;
  unsigned r = v.u + 0x7fffu + ((v.u >> 16) & 1u);
  return (unsigned short)(r >> 16);
}
__device__ inline float bf2f(unsigned short h) {
  union { unsigned u; float f; } v; v.u = ((unsigned)h) << 16; return v.f;
}
__device__ inline float gelu_f(float x) {
  return x * 0.5f * (1.f + erff(x * 0.70710678f));
}

// ---------------- LayerNorm over last dim (128), bf16 output ----------------
__global__ __launch_bounds__(128) void k_ln(const float* __restrict__ x,
                                            const float* __restrict__ g,
                                            const float* __restrict__ bb,
                                            unsigned short* __restrict__ y) {
  int row = blockIdx.x;
  int t = threadIdx.x;
  float v = x[(size_t)row * 128 + t];
  float s = v, s2 = v * v;
  for (int off = 32; off > 0; off >>= 1) {
    s += __shfl_down(s, off, 64);
    s2 += __shfl_down(s2, off, 64);
  }
  __shared__ float ps[2], ps2[2];
  int wid = t >> 6, lane = t & 63;
  if (lane == 0) { ps[wid] = s; ps2[wid] = s2; }
  __syncthreads();
  float S = ps[0] + ps[1], S2 = ps2[0] + ps2[1];
  float mean = S * (1.f / 128.f);
  float var = S2 * (1.f / 128.f) - mean * mean;
  float r = rsqrtf(var + 1e-5f);
  y[(size_t)row * 128 + t] = bf16r((v - mean) * r * g[t] + bb[t]);
}

// ---------------- means of un(bf16) over ny (blk<512) / nx (else) ----------------
__global__ __launch_bounds__(128) void k_means(const unsigned short* __restrict__ un,
                                               float* __restrict__ mx, float* __restrict__ my) {
  int blk = blockIdx.x;
  int c = threadIdx.x;
  if (blk < 512) {
    const unsigned short* p = un + (size_t)blk * 16384 + c;
    float s = 0;
    for (int j = 0; j < 128; j++) s += bf2f(p[(size_t)j * 128]);
    mx[(size_t)blk * 128 + c] = s * (1.f / 128.f);
  } else {
    int bj = blk - 512;
    int b = bj >> 7, j = bj & 127;
    const unsigned short* p = un + (size_t)b * 2097152 + (size_t)j * 128 + c;
    float s = 0;
    for (int i = 0; i < 128; i++) s += bf2f(p[(size_t)i * 16384]);
    my[(size_t)bj * 128 + c] = s * (1.f / 128.f);
  }
}

// ---------------- weight prep: WvT / Wo1T / Wo2T bf16 transposes + colsum ----------------
__global__ __launch_bounds__(256) void k_wprep(const float* __restrict__ Wv,
                                               const float* __restrict__ Wo1,
                                               const float* __restrict__ Wo2,
                                               unsigned short* __restrict__ WvT,
                                               unsigned short* __restrict__ Wo1T,
                                               unsigned short* __restrict__ Wo2T,
                                               float* __restrict__ scol) {
  int blk = blockIdx.x, t = threadIdx.x;
  if (blk < 256) {
    int idx = blk * 256 + t;            // 65536: WvT[hc][d] = Wv[d][hc]
    int c = idx >> 7, r = idx & 127;
    WvT[(size_t)c * 128 + r] = bf16r(Wv[(size_t)r * 512 + c]);
  } else if (blk < 512) {
    int idx = (blk - 256) * 256 + t;    // 65536: Wo1T[n][k] = Wo1[k][n]
    int n = idx >> 9, k = idx & 511;
    Wo1T[(size_t)n * 512 + k] = bf16r(Wo1[(size_t)k * 128 + n]);
  } else if (blk < 576) {
    int idx = (blk - 512) * 256 + t;    // 16384: Wo2T[n][k] = Wo2[k][n]
    int n = idx >> 7, k = idx & 127;
    Wo2T[n * 128 + k] = bf16r(Wo2[k * 128 + n]);
  } else {
    if (t < 128) {
      float a = 0;
      for (int k = 0; k < 512; k++) a += bf2f(bf16r(Wo1[k * 128 + t]));
      scol[t] = a;
    }
  }
}

// ---------------- fp32 GEMM, z-batched (small shapes only) ----------------
__global__ __launch_bounds__(256) void k_gemmz(const float* __restrict__ A0,
                                               const float* __restrict__ B0,
                                               float* __restrict__ C0,
                                               const float* __restrict__ A1,
                                               const float* __restrict__ B1,
                                               float* __restrict__ C1,
                                               int K, int lda, int ldb, int ldc) {
  const float* A = blockIdx.z ? A1 : A0;
  const float* Bm = blockIdx.z ? B1 : B0;
  float* C = blockIdx.z ? C1 : C0;
  __shared__ float As[16][64];
  __shared__ float Bs[16][64];
  int tid = threadIdx.x;
  int n0 = blockIdx.x * 64, m0 = blockIdx.y * 64;
  int tx = tid & 15, ty = tid >> 4;
  float acc[4][4] = {};
  int la_m = tid >> 2, la_k = (tid & 3) * 4;
  int lb_k = tid >> 4, lb_n = (tid & 15) * 4;
  for (int k0 = 0; k0 < K; k0 += 16) {
    float4 a4 = *(const float4*)(A + (size_t)(m0 + la_m) * lda + k0 + la_k);
    As[la_k + 0][la_m] = a4.x; As[la_k + 1][la_m] = a4.y;
    As[la_k + 2][la_m] = a4.z; As[la_k + 3][la_m] = a4.w;
    float4 b4 = *(const float4*)(Bm + (size_t)(k0 + lb_k) * ldb + n0 + lb_n);
    *(float4*)&Bs[lb_k][lb_n] = b4;
    __syncthreads();
#pragma unroll
    for (int kk = 0; kk < 16; kk++) {
      float4 av = *(const float4*)&As[kk][ty * 4];
      float4 bv = *(const float4*)&Bs[kk][tx * 4];
      float a[4] = {av.x, av.y, av.z, av.w};
      float b[4] = {bv.x, bv.y, bv.z, bv.w};
#pragma unroll
      for (int i = 0; i < 4; i++)
#pragma unroll
        for (int j = 0; j < 4; j++) acc[i][j] += a[i] * b[j];
    }
    __syncthreads();
  }
#pragma unroll
  for (int i = 0; i < 4; i++) {
    float4 o;
    o.x = acc[i][0]; o.y = acc[i][1]; o.z = acc[i][2]; o.w = acc[i][3];
    *(float4*)(C + (size_t)(m0 + ty * 4 + i) * ldc + n0 + tx * 4) = o;
  }
}

// ---------------- pooling MLP, y-batched ----------------
__global__ __launch_bounds__(128) void k_pool2(const float* __restrict__ in0, const float* __restrict__ in1,
                                               const float* __restrict__ Wc0, const float* __restrict__ Wc1,
                                               const float* __restrict__ g0, const float* __restrict__ g1,
                                               const float* __restrict__ bb0, const float* __restrict__ bb1,
                                               const float* __restrict__ W10, const float* __restrict__ W11,
                                               const float* __restrict__ b10, const float* __restrict__ b11,
                                               const float* __restrict__ W20, const float* __restrict__ W21,
                                               const float* __restrict__ b20, const float* __restrict__ b21,
                                               float* __restrict__ o0, float* __restrict__ o1) {
  int sel = blockIdx.y;
  const float* in = sel ? in1 : in0;  const float* Wc = sel ? Wc1 : Wc0;
  const float* g = sel ? g1 : g0;     const float* bb = sel ? bb1 : bb0;
  const float* W1 = sel ? W11 : W10;  const float* b1 = sel ? b11 : b10;
  const float* W2 = sel ? W21 : W20;  const float* b2 = sel ? b21 : b20;
  float* out = sel ? o1 : o0;
  int row = blockIdx.x;
  int t = threadIdx.x;
  __shared__ float xin[128], h1[128], h3[128];
  __shared__ float ps[2], ps2[2];
  xin[t] = in[(size_t)row * 128 + t];
  __syncthreads();
  float a = 0;
  for (int k = 0; k < 128; k++) a += xin[k] * Wc[k * 128 + t];
  float s = a, s2 = a * a;
  for (int off = 32; off > 0; off >>= 1) {
    s += __shfl_down(s, off, 64);
    s2 += __shfl_down(s2, off, 64);
  }
  if ((t & 63) == 0) { ps[t >> 6] = s; ps2[t >> 6] = s2; }
  __syncthreads();
  float S = ps[0] + ps[1], S2 = ps2[0] + ps2[1];
  float mean = S * (1.f / 128.f);
  float var = S2 * (1.f / 128.f) - mean * mean;
  float r = rsqrtf(var + 1e-5f);
  h1[t] = (a - mean) * r * g[t] + bb[t];
  __syncthreads();
  float u1 = b1[t], u2 = b1[t + 128];
  for (int k = 0; k < 128; k++) {
    float hv = h1[k];
    u1 += hv * W1[k * 256 + t];
    u2 += hv * W1[k * 256 + t + 128];
  }
  h3[t] = gelu_f(u1) * u2;
  __syncthreads();
  if (t < 64) {
    float o = b2[t];
    for (int k = 0; k < 128; k++) o += h3[k] * W2[k * 64 + t];
    out[(size_t)row * 64 + t] = o;
  }
}

// ---------------- rotary, y-batched ----------------
__global__ __launch_bounds__(192) void k_rot2(const float* __restrict__ qk0, const float* __restrict__ qk1,
                                              const float* __restrict__ pos0, const float* __restrict__ pos1,
                                              float* __restrict__ qr0, float* __restrict__ qr1,
                                              float* __restrict__ kr0, float* __restrict__ kr1) {
  int sel = blockIdx.y;
  const float* qk = sel ? qk1 : qk0;
  const float* pos = sel ? pos1 : pos0;
  float* qr = sel ? qr1 : qr0;
  float* kr = sel ? kr1 : kr0;
  int bn = blockIdx.x;
  int b = bn >> 7, n = bn & 127;
  int d = threadIdx.x;
  int fi = d % 96;
  float inv = expf(-logf(10000.f) * ((float)fi / 96.f));
  float f = pos[n] * 64.f * inv;
  float cs = cosf(f), sn = sinf(f);
  int partner = d < 96 ? d + 96 : d - 96;
  float sgn = d < 96 ? -1.f : 1.f;
  for (int h = 0; h < 8; h++) {
    float q = qk[(size_t)bn * 3072 + h * 192 + d];
    float qp = qk[(size_t)bn * 3072 + h * 192 + partner];
    float kx = qk[(size_t)bn * 3072 + 1536 + h * 192 + d];
    float kp = qk[(size_t)bn * 3072 + 1536 + h * 192 + partner];
    size_t o = ((size_t)(b * 8 + h) * 128 + n) * 192 + d;
    qr[o] = q * cs + sgn * qp * sn;
    kr[o] = kx * cs + sgn * kp * sn;
  }
}

// ---------------- batched Q@K^T per (b,h), bf16 output, z-batched x/y ----------------
__global__ __launch_bounds__(256) void k_qkt2(const float* __restrict__ Q0, const float* __restrict__ K0,
                                              unsigned short* __restrict__ C0,
                                              const float* __restrict__ Q1, const float* __restrict__ K1,
                                              unsigned short* __restrict__ C1) {
  int z = blockIdx.z;
  int bh = z & 31;
  const float* Qb = (z < 32 ? Q0 : Q1) + (size_t)bh * 128 * KDD;
  const float* Kb = (z < 32 ? K0 : K1) + (size_t)bh * 128 * KDD;
  unsigned short* Cb = (z < 32 ? C0 : C1) + (size_t)bh * 128 * 128;
  __shared__ float As[16][64];
  __shared__ float Bs[16][64];
  int tid = threadIdx.x;
  int i0 = blockIdx.y * 64, j0 = blockIdx.x * 64;
  int tx = tid & 15, ty = tid >> 4;
  float acc[4][4] = {};
  int l_m = tid >> 2, l_k = (tid & 3) * 4;
  for (int k0 = 0; k0 < KDD; k0 += 16) {
    float4 a4 = *(const float4*)(Qb + (size_t)(i0 + l_m) * KDD + k0 + l_k);
    As[l_k + 0][l_m] = a4.x; As[l_k + 1][l_m] = a4.y;
    As[l_k + 2][l_m] = a4.z; As[l_k + 3][l_m] = a4.w;
    float4 b4 = *(const float4*)(Kb + (size_t)(j0 + l_m) * KDD + k0 + l_k);
    Bs[l_k + 0][l_m] = b4.x; Bs[l_k + 1][l_m] = b4.y;
    Bs[l_k + 2][l_m] = b4.z; Bs[l_k + 3][l_m] = b4.w;
    __syncthreads();
#pragma unroll
    for (int kk = 0; kk < 16; kk++) {
      float4 av = *(const float4*)&As[kk][ty * 4];
      float4 bv = *(const float4*)&Bs[kk][tx * 4];
      float a[4] = {av.x, av.y, av.z, av.w};
      float b[4] = {bv.x, bv.y, bv.z, bv.w};
#pragma unroll
      for (int i = 0; i < 4; i++)
#pragma unroll
        for (int j = 0; j < 4; j++) acc[i][j] += a[i] * b[j];
    }
    __syncthreads();
  }
#pragma unroll
  for (int i = 0; i < 4; i++) {
    unsigned h0 = bf16r(acc[i][0]), h1 = bf16r(acc[i][1]);
    unsigned h2 = bf16r(acc[i][2]), h3 = bf16r(acc[i][3]);
    uint2 pk;
    pk.x = h0 | (h1 << 16);
    pk.y = h2 | (h3 << 16);
    *(uint2*)(Cb + (size_t)(i0 + ty * 4 + i) * 128 + j0 + tx * 4) = pk;
  }
}

// ==== xor-swizzled LDS helpers: logical (row 0..127, col 0..127) on a 128x128 ushort tile ====
// phys = row*128 + ((c8 ^ (row&15))<<3) + (col&7), c8 = col>>3

// ---- vT[hc][(b,j,m)] = sum_d WvT[hc][d] * un[(b,j,m)][d]  (== (un@Wv)^T) ----
__global__ __launch_bounds__(256) void k_vt(const unsigned short* __restrict__ WvT,
                                            const unsigned short* __restrict__ un,
                                            unsigned short* __restrict__ vT) {
  int nt = blockIdx.x;   // bjm tile (0..511)
  int mt = blockIdx.y;   // hc tile (0..3)
  __shared__ __align__(16) unsigned short As[16384];
  __shared__ __align__(16) unsigned short Bs[16384];
  int tid = threadIdx.x;
  int w = tid >> 6, lane = tid & 63, quad = lane >> 4, l16 = lane & 15;
  {
    int r = tid >> 1, half = tid & 1;
    const unsigned short* sa = WvT + (size_t)(mt * 128 + r) * 128 + half * 64;
    const unsigned short* sbp = un + (size_t)(nt * 128 + r) * 128 + half * 64;
#pragma unroll
    for (int q = 0; q < 8; q++) {
      int c8 = half * 8 + q;
      int ph = ((c8 ^ (r & 15)) << 3);
      *(uint4*)&As[r * 128 + ph] = *(const uint4*)(sa + q * 8);
      *(uint4*)&Bs[r * 128 + ph] = *(const uint4*)(sbp + q * 8);
    }
  }
  __syncthreads();
  facc zf = {0.f, 0.f, 0.f, 0.f};
  facc acc[2][8];
#pragma unroll
  for (int a = 0; a < 2; a++)
#pragma unroll
    for (int bq = 0; bq < 8; bq++) acc[a][bq] = zf;
#pragma unroll
  for (int k0 = 0; k0 < 4; k0++) {
    bfrag av[2];
#pragma unroll
    for (int it = 0; it < 2; it++) {
      int row = (w + it * 4) * 16 + l16;
      av[it] = *(const bfrag*)&As[row * 128 + ((((k0 * 4 + quad) ^ l16)) << 3)];
    }
#pragma unroll
    for (int nt8 = 0; nt8 < 8; nt8++) {
      int row = nt8 * 16 + l16;
      bfrag bv = *(const bfrag*)&Bs[row * 128 + ((((k0 * 4 + quad) ^ l16)) << 3)];
      acc[0][nt8] = __builtin_amdgcn_mfma_f32_16x16x32_bf16(av[0], bv, acc[0][nt8], 0, 0, 0);
      acc[1][nt8] = __builtin_amdgcn_mfma_f32_16x16x32_bf16(av[1], bv, acc[1][nt8], 0, 0, 0);
    }
  }
  __syncthreads();
#pragma unroll
  for (int it = 0; it < 2; it++)
#pragma unroll
    for (int nt8 = 0; nt8 < 8; nt8++)
#pragma unroll
      for (int rr = 0; rr < 4; rr++) {
        int row = (w + it * 4) * 16 + quad * 4 + rr;
        int col = nt8 * 16 + l16;
        As[row * 128 + ((((col >> 3) ^ (row & 15)) << 3)) + (col & 7)] = bf16r(acc[it][nt8][rr]);
      }
  __syncthreads();
  {
    int r = tid >> 1, half = tid & 1;
    unsigned short* dst = vT + (size_t)(mt * 128 + r) * 65536 + (size_t)nt * 128 + half * 64;
#pragma unroll
    for (int q = 0; q < 8; q++) {
      int c8 = half * 8 + q;
      *(uint4*)(dst + q * 8) = *(const uint4*)&As[r * 128 + ((c8 ^ (r & 15)) << 3)];
    }
  }
}

// ---- fused x/y attend per (bh, 4-c strip): tt'[bh][c][i][l] = kx @ (Vc @ ky^T), + stats ----
__global__ __launch_bounds__(256) void k_fuse12(const unsigned short* __restrict__ kxall,
                                                const unsigned short* __restrict__ kyall,
                                                const unsigned short* __restrict__ vT,
                                                unsigned short* __restrict__ ttp,
                                                float* __restrict__ sb,
                                                float* __restrict__ s2b) {
  int blk = blockIdx.x;            // 512
  int bh = blk >> 4, strip = blk & 15;
  int b = bh >> 3, h = bh & 7;
  __shared__ __align__(16) unsigned short Ky[16384];
  __shared__ __align__(16) unsigned short Vs[16384];
  __shared__ float sL[128], s2L[128];
  int tid = threadIdx.x;
  int w = tid >> 6, lane = tid & 63, quad = lane >> 4, l16 = lane & 15;
  if (tid < 128) { sL[tid] = 0.f; s2L[tid] = 0.f; }
  {
    int r = tid >> 1, half = tid & 1;
    const unsigned short* s = kyall + (size_t)bh * 16384 + (size_t)r * 128 + half * 64;
#pragma unroll
    for (int q = 0; q < 8; q++) {
      int c8 = half * 8 + q;
      *(uint4*)&Ky[r * 128 + ((c8 ^ (r & 15)) << 3)] = *(const uint4*)(s + q * 8);
    }
  }
  // kx fragments kept in registers for the whole block (reused across c)
  uint4 axf[2][4];
#pragma unroll
  for (int it = 0; it < 2; it++) {
    int i = (w + it * 4) * 16 + l16;
#pragma unroll
    for (int k0 = 0; k0 < 4; k0++)
      axf[it][k0] = *(const uint4*)(kxall + (size_t)bh * 16384 + (size_t)i * 128 + k0 * 32 + quad * 8);
  }
  __syncthreads();
  facc zf = {0.f, 0.f, 0.f, 0.f};
  for (int cc = 0; cc < 4; cc++) {
    int c = strip * 4 + cc;
    if (cc) __syncthreads();
    {
      int r = tid >> 1, half = tid & 1;
      const unsigned short* s = vT + (size_t)(h * 64 + c) * 65536 + (size_t)b * 16384 +
                                (size_t)r * 128 + half * 64;
#pragma unroll
      for (int q = 0; q < 8; q++) {
        int c8 = half * 8 + q;
        *(uint4*)&Vs[r * 128 + ((c8 ^ (r & 15)) << 3)] = *(const uint4*)(s + q * 8);
      }
    }
    __syncthreads();
    // stage 1: S[j][l] = sum_m Vc[j][m] * ky[l][m]
    facc a1[2][8];
#pragma unroll
    for (int a = 0; a < 2; a++)
#pragma unroll
      for (int bq = 0; bq < 8; bq++) a1[a][bq] = zf;
#pragma unroll
    for (int k0 = 0; k0 < 4; k0++) {
      bfrag av[2];
#pragma unroll
      for (int it = 0; it < 2; it++) {
        int row = (w + it * 4) * 16 + l16;
        av[it] = *(const bfrag*)&Vs[row * 128 + (((k0 * 4 + quad) ^ l16) << 3)];
      }
#pragma unroll
      for (int lt = 0; lt < 8; lt++) {
        int row = lt * 16 + l16;
        bfrag bv = *(const bfrag*)&Ky[row * 128 + (((k0 * 4 + quad) ^ l16) << 3)];
        a1[0][lt] = __builtin_amdgcn_mfma_f32_16x16x32_bf16(av[0], bv, a1[0][lt], 0, 0, 0);
        a1[1][lt] = __builtin_amdgcn_mfma_f32_16x16x32_bf16(av[1], bv, a1[1][lt], 0, 0, 0);
      }
    }
    __syncthreads();
    // write S^T into Vs: St[l][j]
#pragma unroll
    for (int it = 0; it < 2; it++)
#pragma unroll
      for (int lt = 0; lt < 8; lt++)
#pragma unroll
        for (int rr = 0; rr < 4; rr++) {
          int j = (w + it * 4) * 16 + quad * 4 + rr;
          int l = lt * 16 + l16;
          Vs[l * 128 + (((j >> 3) ^ (l & 15)) << 3) + (j & 7)] = bf16r(a1[it][lt][rr]);
        }
    __syncthreads();
    // stage 2: D[i][l] = sum_j kx[i][j] * St[l][j]
    facc a2[2][8];
#pragma unroll
    for (int a = 0; a < 2; a++)
#pragma unroll
      for (int bq = 0; bq < 8; bq++) a2[a][bq] = zf;
#pragma unroll
    for (int k0 = 0; k0 < 4; k0++) {
      bfrag av0 = *(const bfrag*)&axf[0][k0];
      bfrag av1 = *(const bfrag*)&axf[1][k0];
#pragma unroll
      for (int lt = 0; lt < 8; lt++) {
        int row = lt * 16 + l16;
        bfrag bv = *(const bfrag*)&Vs[row * 128 + (((k0 * 4 + quad) ^ l16) << 3)];
        a2[0][lt] = __builtin_amdgcn_mfma_f32_16x16x32_bf16(av0, bv, a2[0][lt], 0, 0, 0);
        a2[1][lt] = __builtin_amdgcn_mfma_f32_16x16x32_bf16(av1, bv, a2[1][lt], 0, 0, 0);
      }
    }
    __syncthreads();
    // write D into Vs as [i][l]
#pragma unroll
    for (int it = 0; it < 2; it++)
#pragma unroll
      for (int lt = 0; lt < 8; lt++)
#pragma unroll
        for (int rr = 0; rr < 4; rr++) {
          int i = (w + it * 4) * 16 + quad * 4 + rr;
          int l = lt * 16 + l16;
          Vs[i * 128 + (((l >> 3) ^ (i & 15)) << 3) + (l & 7)] = bf16r(a2[it][lt][rr]);
        }
    __syncthreads();
    // coalesced store + stats
    {
      int r = tid >> 1, half = tid & 1;
      float s = 0.f, s2 = 0.f;
      unsigned short* dst = ttp + ((size_t)(bh * 64 + c) * 128 + r) * 128 + half * 64;
#pragma unroll
      for (int q = 0; q < 8; q++) {
        int c8 = half * 8 + q;
        uint4 v = *(const uint4*)&Vs[r * 128 + ((c8 ^ (r & 15)) << 3)];
        *(uint4*)(dst + q * 8) = v;
        unsigned short* pv = (unsigned short*)&v;
#pragma unroll
        for (int e = 0; e < 8; e++) { float f = bf2f(pv[e]); s += f; s2 += f * f; }
      }
      atomicAdd(&sL[r], s);
      atomicAdd(&s2L[r], s2);
    }
  }
  __syncthreads();
  if (tid < 128) {
    atomicAdd(&sb[b * 128 + tid], sL[tid]);
    atomicAdd(&s2b[b * 128 + tid], s2L[tid]);
  }
}

// ---- tail per (b,i): out[l][:] = gelu(instnorm(tt)[l,:] @ Wo1) @ Wo2 ----
__global__ __launch_bounds__(256) void k_tail2(const unsigned short* __restrict__ ttp,
                                               const unsigned short* __restrict__ Wo1T,
                                               const unsigned short* __restrict__ Wo2T,
                                               float* __restrict__ out,
                                               const float* __restrict__ sb,
                                               const float* __restrict__ s2b,
                                               const float* __restrict__ sc) {
  int blk = blockIdx.x;   // 512
  int b = blk >> 7, i = blk & 127;
  __shared__ __align__(16) unsigned short As[16384];
  __shared__ __align__(16) unsigned short Bs[16384];
  int tid = threadIdx.x;
  int w = tid >> 6, lane = tid & 63, quad = lane >> 4, l16 = lane & 15;
  facc zf = {0.f, 0.f, 0.f, 0.f};
  facc a1[2][8];
#pragma unroll
  for (int a = 0; a < 2; a++)
#pragma unroll
    for (int bq = 0; bq < 8; bq++) a1[a][bq] = zf;
  for (int kc = 0; kc < 4; kc++) {
    if (kc) __syncthreads();
    {
      int r = tid >> 1, half = tid & 1;
      int hc = kc * 128 + r;
      const unsigned short* src = ttp + (((size_t)(b * 8 + (hc >> 6)) * 64 + (hc & 63)) * 128 + i) * 128 + half * 64;
#pragma unroll
      for (int q = 0; q < 8; q++) {
        uint4 v = *(const uint4*)(src + q * 8);
        unsigned short* pv = (unsigned short*)&v;
#pragma unroll
        for (int e = 0; e < 8; e++) {
          int l = half * 64 + q * 8 + e;
          As[l * 128 + (((r >> 3) ^ (l & 15)) << 3) + (r & 7)] = pv[e];
        }
      }
      const unsigned short* sB = Wo1T + (size_t)r * 512 + kc * 128 + half * 64;
#pragma unroll
      for (int q = 0; q < 8; q++) {
        int c8 = half * 8 + q;
        *(uint4*)&Bs[r * 128 + ((c8 ^ (r & 15)) << 3)] = *(const uint4*)(sB + q * 8);
      }
    }
    __syncthreads();
#pragma unroll
    for (int k0 = 0; k0 < 4; k0++) {
      bfrag av[2];
#pragma unroll
      for (int it = 0; it < 2; it++) {
        int row = (w + it * 4) * 16 + l16;
        av[it] = *(const bfrag*)&As[row * 128 + (((k0 * 4 + quad) ^ l16) << 3)];
      }
#pragma unroll
      for (int nt = 0; nt < 8; nt++) {
        int row = nt * 16 + l16;
        bfrag bv = *(const bfrag*)&Bs[row * 128 + (((k0 * 4 + quad) ^ l16) << 3)];
        a1[0][nt] = __builtin_amdgcn_mfma_f32_16x16x32_bf16(av[0], bv, a1[0][nt], 0, 0, 0);
        a1[1][nt] = __builtin_amdgcn_mfma_f32_16x16x32_bf16(av[1], bv, a1[1][nt], 0, 0, 0);
      }
    }
  }
  float S = sb[b * 128 + i], S2 = s2b[b * 128 + i];
  float mean = S * (1.f / 65536.f);
  float var = S2 * (1.f / 65536.f) - mean * mean;
  float rs = rsqrtf(var + 1e-5f);
  __syncthreads();
  // G = gelu(instnorm epilogue), bf16 into As ([l][n1])
#pragma unroll
  for (int it = 0; it < 2; it++)
#pragma unroll
    for (int nt = 0; nt < 8; nt++) {
      int n1 = nt * 16 + l16;
      float scn = sc[n1];
#pragma unroll
      for (int rr = 0; rr < 4; rr++) {
        int l = (w + it * 4) * 16 + quad * 4 + rr;
        float val = (a1[it][nt][rr] - mean * scn) * rs;
        As[l * 128 + (((n1 >> 3) ^ (l & 15)) << 3) + (n1 & 7)] = bf16r(gelu_f(val));
      }
    }
  {
    int r = tid >> 1, half = tid & 1;
    const unsigned short* sB = Wo2T + (size_t)r * 128 + half * 64;
#pragma unroll
    for (int q = 0; q < 8; q++) {
      int c8 = half * 8 + q;
      *(uint4*)&Bs[r * 128 + ((c8 ^ (r & 15)) << 3)] = *(const uint4*)(sB + q * 8);
    }
  }
  __syncthreads();
  facc a2[2][8];
#pragma unroll
  for (int a = 0; a < 2; a++)
#pragma unroll
    for (int bq = 0; bq < 8; bq++) a2[a][bq] = zf;
#pragma unroll
  for (int k0 = 0; k0 < 4; k0++) {
    bfrag av[2];
#pragma unroll
    for (int it = 0; it < 2; it++) {
      int row = (w + it * 4) * 16 + l16;
      av[it] = *(const bfrag*)&As[row * 128 + (((k0 * 4 + quad) ^ l16) << 3)];
    }
#pragma unroll
    for (int nt = 0; nt < 8; nt++) {
      int row = nt * 16 + l16;
      bfrag bv = *(const bfrag*)&Bs[row * 128 + (((k0 * 4 + quad) ^ l16) << 3)];
      a2[0][nt] = __builtin_amdgcn_mfma_f32_16x16x32_bf16(av[0], bv, a2[0][nt], 0, 0, 0);
      a2[1][nt] = __builtin_amdgcn_mfma_f32_16x16x32_bf16(av[1], bv, a2[1][nt], 0, 0, 0);
    }
  }
#pragma unroll
  for (int it = 0; it < 2; it++)
#pragma unroll
    for (int nt = 0; nt < 8; nt++) {
      int n2 = nt * 16 + l16;
#pragma unroll
      for (int rr = 0; rr < 4; rr++) {
        int l = (w + it * 4) * 16 + quad * 4 + rr;
        out[((size_t)(b * 16384 + i * 128 + l)) * 128 + n2] = a2[it][nt][rr];
      }
    }
}

extern "C" void kernel_launch(void* const* d_in, const int* in_sizes, int n_in,
                              void* d_out, int out_size, void* d_ws, size_t ws_size,
                              hipStream_t stream) {
  const float* u = (const float*)d_in[0];
  const float* pos_x = (const float*)d_in[1];
  const float* pos_y = (const float*)d_in[2];
  const float* ln_g = (const float*)d_in[3];
  const float* ln_b = (const float*)d_in[4];
  const float* Wv = (const float*)d_in[5];
  const float* Win = (const float*)d_in[6];
  const float* px_Win = (const float*)d_in[7];
  const float* px_g = (const float*)d_in[8];
  const float* px_b = (const float*)d_in[9];
  const float* px_W1 = (const float*)d_in[10];
  const float* px_b1 = (const float*)d_in[11];
  const float* px_W2 = (const float*)d_in[12];
  const float* px_b2 = (const float*)d_in[13];
  const float* py_Win = (const float*)d_in[14];
  const float* py_g = (const float*)d_in[15];
  const float* py_b = (const float*)d_in[16];
  const float* py_W1 = (const float*)d_in[17];
  const float* py_b1 = (const float*)d_in[18];
  const float* py_W2 = (const float*)d_in[19];
  const float* py_b2 = (const float*)d_in[20];
  const float* Wqk_x = (const float*)d_in[21];
  const float* Wqk_y = (const float*)d_in[22];
  const float* Wo1 = (const float*)d_in[23];
  const float* Wo2 = (const float*)d_in[24];
  float* out = (float*)d_out;

  const size_t NEED = 44868736;  // floats (~180 MB); harness ws is 256 MiB
  if (ws_size < NEED * sizeof(float)) return;
  float* ws = (float*)d_ws;
  unsigned short* un_bf = (unsigned short*)ws;               // [65536][128]
  unsigned short* vT    = (unsigned short*)(ws + 4194304);   // [512][65536]
  unsigned short* ttp   = (unsigned short*)(ws + 20971520);  // [32][64][128][128]
  float* small = ws + 37748736;
  float* mun_x = small;                 // 65536
  float* mun_y = small + 65536;         // 65536
  float* Wcx   = small + 131072;        // 16384
  float* Wcy   = small + 147456;        // 16384
  float* ux    = small + 163840;        // 32768
  float* uy    = small + 196608;        // 32768
  float* qkx   = small + 229376;        // 1572864
  float* qky   = small + 1802240;       // 1572864
  float* qrx   = small + 3375104;       // 786432
  float* krx   = small + 4161536;       // 786432
  float* qry   = small + 4947968;       // 786432
  float* kry   = small + 5734400;       // 786432
  unsigned short* kx_bf = (unsigned short*)(small + 6520832);  // 524288 el
  unsigned short* ky_bf = (unsigned short*)(small + 6782976);  // 524288 el
  unsigned short* WvT   = (unsigned short*)(small + 7045120);  // 65536 el
  unsigned short* Wo1T  = (unsigned short*)(small + 7077888);  // 65536 el
  unsigned short* Wo2T  = (unsigned short*)(small + 7110656);  // 16384 el
  float* sbuf  = small + 7118848;       // 512
  float* s2buf = small + 7119360;       // 512
  float* scol  = small + 7119872;       // 128

  hipMemsetAsync(sbuf, 0, 1024 * sizeof(float), stream);

  // Phase A
  k_ln<<<ROWS, 128, 0, stream>>>(u, ln_g, ln_b, un_bf);
  k_means<<<1024, 128, 0, stream>>>(un_bf, mun_x, mun_y);
  k_wprep<<<577, 256, 0, stream>>>(Wv, Wo1, Wo2, WvT, Wo1T, Wo2T, scol);
  // Wc = Win @ p*_Win (mean commutes with linear maps)
  k_gemmz<<<dim3(2, 2, 2), 256, 0, stream>>>(Win, px_Win, Wcx, Win, py_Win, Wcy,
                                             128, 128, 128, 128);
  k_pool2<<<dim3(512, 2), 128, 0, stream>>>(mun_x, mun_y, Wcx, Wcy, px_g, py_g, px_b, py_b,
                                            px_W1, py_W1, px_b1, py_b1, px_W2, py_W2,
                                            px_b2, py_b2, ux, uy);
  k_gemmz<<<dim3(48, 8, 2), 256, 0, stream>>>(ux, Wqk_x, qkx, uy, Wqk_y, qky,
                                              64, 64, 3072, 3072);
  k_rot2<<<dim3(512, 2), 192, 0, stream>>>(qkx, qky, pos_x, pos_y, qrx, qry, krx, kry);
  k_qkt2<<<dim3(2, 2, 64), 256, 0, stream>>>(qrx, krx, kx_bf, qry, kry, ky_bf);

  // Phase B
  k_vt<<<dim3(512, 4), 256, 0, stream>>>(WvT, un_bf, vT);
  k_fuse12<<<512, 256, 0, stream>>>(kx_bf, ky_bf, vT, ttp, sbuf, s2buf);
  k_tail2<<<512, 256, 0, stream>>>(ttp, Wo1T, Wo2T, out, sbuf, s2buf, scol);
}